// Round 1
// baseline (4522.086 us; speedup 1.0000x reference)
//
#include <hip/hip_runtime.h>
#include <hip/hip_bf16.h>

#define BATCH 2
#define SEQ 1024
#define DMODEL 768
#define DINNER 1536
#define DTRANK 48
#define NSTATE 16
#define NLAYER 2
#define VOCAB 50304
#define NTOK (BATCH * SEQ)   // 2048

// ---------------- embedding gather ----------------
__global__ __launch_bounds__(256) void embed_kernel(const int* __restrict__ tokens,
                                                    const float* __restrict__ wte,
                                                    float* __restrict__ x) {
    int gid = blockIdx.x * 256 + threadIdx.x;       // over NTOK * (DMODEL/4)
    int t = gid / (DMODEL / 4);
    int c = gid % (DMODEL / 4);
    if (t >= NTOK) return;
    int tok = tokens[t];
    ((float4*)x)[t * (DMODEL / 4) + c] = ((const float4*)wte)[(size_t)tok * (DMODEL / 4) + c];
}

// ---------------- RMSNorm (row = 768) ----------------
__global__ __launch_bounds__(256) void rmsnorm_kernel(const float* __restrict__ in,
                                                      float* __restrict__ out) {
    int row = blockIdx.x;
    int tid = threadIdx.x;
    const float* r = in + row * DMODEL;
    float v0 = r[tid], v1 = r[tid + 256], v2 = r[tid + 512];
    float s = v0 * v0 + v1 * v1 + v2 * v2;
    #pragma unroll
    for (int off = 32; off > 0; off >>= 1) s += __shfl_down(s, off);
    __shared__ float red[4];
    int wid = tid >> 6, lane = tid & 63;
    if (lane == 0) red[wid] = s;
    __syncthreads();
    if (tid == 0) {
        float tot = red[0] + red[1] + red[2] + red[3];
        red[0] = 1.0f / sqrtf(tot / (float)DMODEL + 1e-6f);
    }
    __syncthreads();
    float sc = red[0];
    float* o = out + row * DMODEL;
    o[tid] = v0 * sc; o[tid + 256] = v1 * sc; o[tid + 512] = v2 * sc;
}

// ---------------- generic fp32 GEMM: C[M,N] = A[M,K] * B[N,K]^T ----------------
// EPI: 0 = store, 1 = bias + softplus, 2 = accumulate into C
template <int EPI>
__global__ __launch_bounds__(256) void gemm_tn(const float* __restrict__ A, int lda,
                                               const float* __restrict__ B, int ldb,
                                               float* __restrict__ C, int ldc,
                                               int M, int N, int K,
                                               const float* __restrict__ bias) {
    __shared__ float As[16][68];
    __shared__ float Bs[16][68];
    const int tid = threadIdx.x;
    const int m0 = blockIdx.y * 64;
    const int n0 = blockIdx.x * 64;
    const int lr = tid >> 2;            // 0..63 tile row
    const int lq = (tid & 3) * 4;       // k quad base
    const int tm = (tid & 15) * 4;      // micro-tile row
    const int tn = (tid >> 4) * 4;      // micro-tile col
    float acc[4][4] = {};

    for (int k0 = 0; k0 < K; k0 += 16) {
        float4 av = *(const float4*)(A + (m0 + lr) * lda + k0 + lq);
        float4 bv = make_float4(0.f, 0.f, 0.f, 0.f);
        if (n0 + lr < N) bv = *(const float4*)(B + (n0 + lr) * ldb + k0 + lq);
        __syncthreads();
        As[lq + 0][lr] = av.x; As[lq + 1][lr] = av.y; As[lq + 2][lr] = av.z; As[lq + 3][lr] = av.w;
        Bs[lq + 0][lr] = bv.x; Bs[lq + 1][lr] = bv.y; Bs[lq + 2][lr] = bv.z; Bs[lq + 3][lr] = bv.w;
        __syncthreads();
        #pragma unroll
        for (int kk = 0; kk < 16; ++kk) {
            float4 a = *(const float4*)&As[kk][tm];
            float4 b = *(const float4*)&Bs[kk][tn];
            const float* ap = (const float*)&a;
            const float* bp = (const float*)&b;
            #pragma unroll
            for (int i = 0; i < 4; ++i)
                #pragma unroll
                for (int j = 0; j < 4; ++j)
                    acc[i][j] = fmaf(ap[i], bp[j], acc[i][j]);
        }
    }

    #pragma unroll
    for (int i = 0; i < 4; ++i) {
        int m = m0 + tm + i;
        #pragma unroll
        for (int j = 0; j < 4; ++j) {
            int n = n0 + tn + j;
            if (n >= N) continue;
            float v = acc[i][j];
            if (EPI == 0) {
                C[m * ldc + n] = v;
            } else if (EPI == 1) {
                v += bias[n];
                C[m * ldc + n] = (v > 20.f) ? v : log1pf(expf(v));
            } else {
                C[m * ldc + n] += v;
            }
        }
    }
}

// ---------------- causal depthwise conv (D_CONV=4) + SiLU ----------------
__global__ __launch_bounds__(256) void conv_silu_kernel(const float* __restrict__ xz,
                                                        const float* __restrict__ cw,  // (DINNER,4)
                                                        const float* __restrict__ cb,  // (DINNER)
                                                        float* __restrict__ xs) {
    int gid = blockIdx.x * 256 + threadIdx.x;  // over NTOK*DINNER
    int d = gid % DINNER;
    int t = gid / DINNER;
    if (t >= NTOK) return;
    int l = t & (SEQ - 1);
    int tb = t - l;
    float4 w = ((const float4*)cw)[d];
    const float* wp = (const float*)&w;
    float acc = cb[d];
    #pragma unroll
    for (int k = 0; k < 4; ++k) {
        int lk = l - 3 + k;
        float v = (lk >= 0) ? xz[(tb + lk) * (2 * DINNER) + d] : 0.f;
        acc = fmaf(wp[k], v, acc);
    }
    xs[t * DINNER + d] = acc / (1.f + expf(-acc));
}

// ---------------- selective scan: 16 lanes per (b,d), one state n each ----------------
__global__ __launch_bounds__(256) void scan_kernel(const float* __restrict__ xs,
                                                   const float* __restrict__ dt,
                                                   const float* __restrict__ xdbl,  // (NTOK,80): B@48, C@64
                                                   const float* __restrict__ A_log, // (DINNER,16)
                                                   const float* __restrict__ Dp,    // (DINNER)
                                                   float* __restrict__ y) {
    int gid = blockIdx.x * 256 + threadIdx.x;  // B*DINNER*16 threads
    int n = gid & 15;
    int grp = gid >> 4;            // 0 .. B*DINNER-1
    int d = grp % DINNER;
    int b = grp / DINNER;
    float A = -expf(A_log[d * NSTATE + n]);
    float Dv = Dp[d];
    float h = 0.f;
    int base = b * SEQ;
    for (int l = 0; l < SEQ; ++l) {
        int t = base + l;
        float dtv = dt[t * DINNER + d];
        float xv  = xs[t * DINNER + d];
        float Bv  = xdbl[t * 80 + DTRANK + n];
        float Cv  = xdbl[t * 80 + DTRANK + NSTATE + n];
        float dA = expf(dtv * A);
        h = fmaf(h, dA, dtv * Bv * xv);
        float p = h * Cv;
        p += __shfl_xor(p, 1, 16);
        p += __shfl_xor(p, 2, 16);
        p += __shfl_xor(p, 4, 16);
        p += __shfl_xor(p, 8, 16);
        if (n == 0) y[t * DINNER + d] = p + Dv * xv;
    }
}

// ---------------- gating: g = y * silu(z) ----------------
__global__ __launch_bounds__(256) void gate_kernel(const float* __restrict__ y,
                                                   const float* __restrict__ xz,
                                                   float* __restrict__ g) {
    int gid = blockIdx.x * 256 + threadIdx.x;  // over NTOK*DINNER
    int d = gid % DINNER;
    int t = gid / DINNER;
    if (t >= NTOK) return;
    float z = xz[t * (2 * DINNER) + DINNER + d];
    g[gid] = y[gid] * z / (1.f + expf(-z));
}

extern "C" void kernel_launch(void* const* d_in, const int* in_sizes, int n_in,
                              void* d_out, int out_size, void* d_ws, size_t ws_size,
                              hipStream_t stream) {
    const int*   tokens     = (const int*)d_in[0];
    const float* wte        = (const float*)d_in[1];
    const float* in_proj_w  = (const float*)d_in[2];   // (2, 3072, 768)
    const float* conv_w     = (const float*)d_in[3];   // (2, 1536, 1, 4)
    const float* conv_b     = (const float*)d_in[4];   // (2, 1536)
    const float* x_proj_w   = (const float*)d_in[5];   // (2, 80, 1536)
    const float* dt_proj_w  = (const float*)d_in[6];   // (2, 1536, 48)
    const float* dt_proj_b  = (const float*)d_in[7];   // (2, 1536)
    const float* out_proj_w = (const float*)d_in[8];   // (2, 768, 1536)
    const float* A_log      = (const float*)d_in[9];   // (2, 1536, 16)
    const float* Dparam     = (const float*)d_in[10];  // (2, 1536)
    const float* lm_head_w  = (const float*)d_in[11];  // (50304, 768)
    float* out = (float*)d_out;

    float* ws   = (float*)d_ws;
    float* x    = ws;                          // NTOK*DMODEL
    float* xn   = x    + NTOK * DMODEL;        // NTOK*DMODEL
    float* xz   = xn   + NTOK * DMODEL;        // NTOK*2*DINNER
    float* xs   = xz   + NTOK * 2 * DINNER;    // NTOK*DINNER
    float* xdbl = xs   + NTOK * DINNER;        // NTOK*80
    float* dtb  = xdbl + NTOK * 80;            // NTOK*DINNER
    float* yb   = dtb  + NTOK * DINNER;        // NTOK*DINNER

    // embed
    embed_kernel<<<NTOK * (DMODEL / 4) / 256, 256, 0, stream>>>(tokens, wte, x);

    for (int i = 0; i < NLAYER; ++i) {
        const float* inw  = in_proj_w  + (size_t)i * 2 * DINNER * DMODEL;
        const float* cw   = conv_w     + (size_t)i * DINNER * 4;
        const float* cb   = conv_b     + (size_t)i * DINNER;
        const float* xpw  = x_proj_w   + (size_t)i * (DTRANK + 2 * NSTATE) * DINNER;
        const float* dtpw = dt_proj_w  + (size_t)i * DINNER * DTRANK;
        const float* dtpb = dt_proj_b  + (size_t)i * DINNER;
        const float* outw = out_proj_w + (size_t)i * DMODEL * DINNER;
        const float* alog = A_log      + (size_t)i * DINNER * NSTATE;
        const float* dpar = Dparam     + (size_t)i * DINNER;

        rmsnorm_kernel<<<NTOK, 256, 0, stream>>>(x, xn);
        // xz = xn @ in_w^T : (2048, 3072)
        gemm_tn<0><<<dim3(2 * DINNER / 64, NTOK / 64), 256, 0, stream>>>(
            xn, DMODEL, inw, DMODEL, xz, 2 * DINNER, NTOK, 2 * DINNER, DMODEL, nullptr);
        // conv + silu -> xs
        conv_silu_kernel<<<NTOK * DINNER / 256, 256, 0, stream>>>(xz, cw, cb, xs);
        // x_dbl = xs @ xp_w^T : (2048, 80)
        gemm_tn<0><<<dim3(2, NTOK / 64), 256, 0, stream>>>(
            xs, DINNER, xpw, DINNER, xdbl, 80, NTOK, 80, DINNER, nullptr);
        // dt = softplus(x_dbl[:, :48] @ dtp_w^T + b) : (2048, 1536)
        gemm_tn<1><<<dim3(DINNER / 64, NTOK / 64), 256, 0, stream>>>(
            xdbl, 80, dtpw, DTRANK, dtb, DINNER, NTOK, DINNER, DTRANK, dtpb);
        // selective scan -> yb
        scan_kernel<<<BATCH * DINNER * NSTATE / 256, 256, 0, stream>>>(
            xs, dtb, xdbl, alog, dpar, yb);
        // g = yb * silu(z) -> xs (reuse)
        gate_kernel<<<NTOK * DINNER / 256, 256, 0, stream>>>(yb, xz, xs);
        // x += g @ out_w^T
        gemm_tn<2><<<dim3(DMODEL / 64, NTOK / 64), 256, 0, stream>>>(
            xs, DINNER, outw, DINNER, x, DMODEL, NTOK, DMODEL, DINNER, nullptr);
    }

    // final norm + lm_head
    rmsnorm_kernel<<<NTOK, 256, 0, stream>>>(x, xn);
    gemm_tn<0><<<dim3(VOCAB / 64, NTOK / 64), 256, 0, stream>>>(
        xn, DMODEL, lm_head_w, DMODEL, out, VOCAB, NTOK, VOCAB, DMODEL, nullptr);
}

// Round 2
// 2181.956 us; speedup vs baseline: 2.0725x; 2.0725x over previous
//
#include <hip/hip_runtime.h>
#include <hip/hip_bf16.h>

#define BATCH 2
#define SEQ 1024
#define DMODEL 768
#define DINNER 1536
#define DTRANK 48
#define NSTATE 16
#define NLAYER 2
#define VOCAB 50304
#define NTOK (BATCH * SEQ)   // 2048

typedef __attribute__((ext_vector_type(8))) short short8;
typedef __attribute__((ext_vector_type(4))) float f32x4;

__device__ __forceinline__ unsigned short f2bf(float f) {
    union { float f; unsigned u; } v; v.f = f;
    unsigned r = v.u + 0x7fffu + ((v.u >> 16) & 1u);
    return (unsigned short)(r >> 16);
}

// ---------------- fp32 -> bf16 conversion (8 elems/thread) ----------------
__global__ __launch_bounds__(256) void cvt_bf16_kernel(const float* __restrict__ in,
                                                       unsigned short* __restrict__ out,
                                                       int n8) {
    int i = blockIdx.x * 256 + threadIdx.x;
    if (i >= n8) return;
    const float4* p = (const float4*)in + 2 * (size_t)i;
    float4 a = p[0], b = p[1];
    union { unsigned short us[8]; uint4 v; } o;
    o.us[0] = f2bf(a.x); o.us[1] = f2bf(a.y); o.us[2] = f2bf(a.z); o.us[3] = f2bf(a.w);
    o.us[4] = f2bf(b.x); o.us[5] = f2bf(b.y); o.us[6] = f2bf(b.z); o.us[7] = f2bf(b.w);
    ((uint4*)out)[i] = o.v;
}

// ---------------- bf16 MFMA GEMM: C[M,N] (+)= A[M,K] * B[N,K]^T ----------------
// m97 structure: 128x128 tile, BK=32, 4 waves, global_load_lds width=16.
// Requires M%128==0, N%128==0, K%32==0. EPI: 0 = store, 2 = accumulate.
template <int EPI>
__global__ __launch_bounds__(256) void gemm_bf16(const unsigned short* __restrict__ A, int lda,
                                                 const unsigned short* __restrict__ B, int ldb,
                                                 float* __restrict__ C, int ldc,
                                                 int K) {
    __shared__ unsigned short As[128 * 32];
    __shared__ unsigned short Bs[128 * 32];
    const int tid = threadIdx.x;
    const int lane = tid & 63;
    const int wave = tid >> 6;
    const int m0 = blockIdx.y * 128;
    const int n0 = blockIdx.x * 128;
    const int wr = (wave >> 1) * 64;   // wave row offset in tile
    const int wc = (wave & 1) * 64;    // wave col offset in tile

    f32x4 acc[4][4] = {};

    for (int k0 = 0; k0 < K; k0 += 32) {
        __syncthreads();   // all waves done reading previous tile
        #pragma unroll
        for (int j = 0; j < 2; ++j) {
            int c = j * 256 + tid;          // chunk 0..511; row = c>>2, kchunk = c&3
            int row = c >> 2;
            int kc = (c & 3) * 8;
            __builtin_amdgcn_global_load_lds(
                (const __attribute__((address_space(1))) unsigned int*)(A + (size_t)(m0 + row) * lda + k0 + kc),
                (__attribute__((address_space(3))) unsigned int*)(As + c * 8), 16, 0, 0);
            __builtin_amdgcn_global_load_lds(
                (const __attribute__((address_space(1))) unsigned int*)(B + (size_t)(n0 + row) * ldb + k0 + kc),
                (__attribute__((address_space(3))) unsigned int*)(Bs + c * 8), 16, 0, 0);
        }
        __syncthreads();   // drains vmcnt -> LDS tile ready

        short8 a[4], b[4];
        #pragma unroll
        for (int i = 0; i < 4; ++i)
            a[i] = *(const short8*)(As + (wr + i * 16 + (lane & 15)) * 32 + (lane >> 4) * 8);
        #pragma unroll
        for (int i = 0; i < 4; ++i)
            b[i] = *(const short8*)(Bs + (wc + i * 16 + (lane & 15)) * 32 + (lane >> 4) * 8);
        #pragma unroll
        for (int i = 0; i < 4; ++i)
            #pragma unroll
            for (int j = 0; j < 4; ++j)
                acc[i][j] = __builtin_amdgcn_mfma_f32_16x16x32_bf16(a[i], b[j], acc[i][j], 0, 0, 0);
    }

    // C/D layout (m89-verified): col = lane&15, row = (lane>>4)*4 + reg
    const int row_base = m0 + wr + (lane >> 4) * 4;
    const int col_base = n0 + wc + (lane & 15);
    #pragma unroll
    for (int i = 0; i < 4; ++i)
        #pragma unroll
        for (int j = 0; j < 4; ++j)
            #pragma unroll
            for (int q = 0; q < 4; ++q) {
                size_t idx = (size_t)(row_base + i * 16 + q) * ldc + col_base + j * 16;
                if (EPI == 0) C[idx] = acc[i][j][q];
                else          C[idx] += acc[i][j][q];
            }
}

// ---------------- embedding gather ----------------
__global__ __launch_bounds__(256) void embed_kernel(const int* __restrict__ tokens,
                                                    const float* __restrict__ wte,
                                                    float* __restrict__ x) {
    int gid = blockIdx.x * 256 + threadIdx.x;       // over NTOK * (DMODEL/4)
    int t = gid / (DMODEL / 4);
    int c = gid % (DMODEL / 4);
    if (t >= NTOK) return;
    int tok = tokens[t];
    ((float4*)x)[t * (DMODEL / 4) + c] = ((const float4*)wte)[(size_t)tok * (DMODEL / 4) + c];
}

// ---------------- RMSNorm (row = 768) ----------------
__global__ __launch_bounds__(256) void rmsnorm_kernel(const float* __restrict__ in,
                                                      float* __restrict__ out) {
    int row = blockIdx.x;
    int tid = threadIdx.x;
    const float* r = in + row * DMODEL;
    float v0 = r[tid], v1 = r[tid + 256], v2 = r[tid + 512];
    float s = v0 * v0 + v1 * v1 + v2 * v2;
    #pragma unroll
    for (int off = 32; off > 0; off >>= 1) s += __shfl_down(s, off);
    __shared__ float red[4];
    int wid = tid >> 6, lane = tid & 63;
    if (lane == 0) red[wid] = s;
    __syncthreads();
    if (tid == 0) {
        float tot = red[0] + red[1] + red[2] + red[3];
        red[0] = 1.0f / sqrtf(tot / (float)DMODEL + 1e-6f);
    }
    __syncthreads();
    float sc = red[0];
    float* o = out + row * DMODEL;
    o[tid] = v0 * sc; o[tid + 256] = v1 * sc; o[tid + 512] = v2 * sc;
}

// ---------------- fp32 GEMM (small shapes): C[M,N] = A[M,K]*B[N,K]^T ----------------
// EPI: 0 = store, 1 = bias + softplus
template <int EPI>
__global__ __launch_bounds__(256) void gemm_tn(const float* __restrict__ A, int lda,
                                               const float* __restrict__ B, int ldb,
                                               float* __restrict__ C, int ldc,
                                               int M, int N, int K,
                                               const float* __restrict__ bias) {
    __shared__ float As[16][68];
    __shared__ float Bs[16][68];
    const int tid = threadIdx.x;
    const int m0 = blockIdx.y * 64;
    const int n0 = blockIdx.x * 64;
    const int lr = tid >> 2;
    const int lq = (tid & 3) * 4;
    const int tm = (tid & 15) * 4;
    const int tn = (tid >> 4) * 4;
    float acc[4][4] = {};

    for (int k0 = 0; k0 < K; k0 += 16) {
        float4 av = *(const float4*)(A + (m0 + lr) * lda + k0 + lq);
        float4 bv = make_float4(0.f, 0.f, 0.f, 0.f);
        if (n0 + lr < N) bv = *(const float4*)(B + (n0 + lr) * ldb + k0 + lq);
        __syncthreads();
        As[lq + 0][lr] = av.x; As[lq + 1][lr] = av.y; As[lq + 2][lr] = av.z; As[lq + 3][lr] = av.w;
        Bs[lq + 0][lr] = bv.x; Bs[lq + 1][lr] = bv.y; Bs[lq + 2][lr] = bv.z; Bs[lq + 3][lr] = bv.w;
        __syncthreads();
        #pragma unroll
        for (int kk = 0; kk < 16; ++kk) {
            float4 a = *(const float4*)&As[kk][tm];
            float4 b = *(const float4*)&Bs[kk][tn];
            const float* ap = (const float*)&a;
            const float* bp = (const float*)&b;
            #pragma unroll
            for (int i = 0; i < 4; ++i)
                #pragma unroll
                for (int j = 0; j < 4; ++j)
                    acc[i][j] = fmaf(ap[i], bp[j], acc[i][j]);
        }
    }

    #pragma unroll
    for (int i = 0; i < 4; ++i) {
        int m = m0 + tm + i;
        #pragma unroll
        for (int j = 0; j < 4; ++j) {
            int n = n0 + tn + j;
            if (n >= N) continue;
            float v = acc[i][j];
            if (EPI == 0) {
                C[m * ldc + n] = v;
            } else {
                v += bias[n];
                C[m * ldc + n] = (v > 20.f) ? v : log1pf(expf(v));
            }
        }
    }
}

// ---------------- causal depthwise conv (D_CONV=4) + SiLU ----------------
__global__ __launch_bounds__(256) void conv_silu_kernel(const float* __restrict__ xz,
                                                        const float* __restrict__ cw,
                                                        const float* __restrict__ cb,
                                                        float* __restrict__ xs) {
    int gid = blockIdx.x * 256 + threadIdx.x;  // over NTOK*DINNER
    int d = gid % DINNER;
    int t = gid / DINNER;
    if (t >= NTOK) return;
    int l = t & (SEQ - 1);
    int tb = t - l;
    float4 w = ((const float4*)cw)[d];
    const float* wp = (const float*)&w;
    float acc = cb[d];
    #pragma unroll
    for (int k = 0; k < 4; ++k) {
        int lk = l - 3 + k;
        float v = (lk >= 0) ? xz[(tb + lk) * (2 * DINNER) + d] : 0.f;
        acc = fmaf(wp[k], v, acc);
    }
    xs[t * DINNER + d] = acc / (1.f + expf(-acc));
}

// ---------------- selective scan: 16 lanes per (b,d), one state n each ----------------
__global__ __launch_bounds__(256) void scan_kernel(const float* __restrict__ xs,
                                                   const float* __restrict__ dt,
                                                   const float* __restrict__ xdbl,
                                                   const float* __restrict__ A_log,
                                                   const float* __restrict__ Dp,
                                                   float* __restrict__ y) {
    int gid = blockIdx.x * 256 + threadIdx.x;  // B*DINNER*16 threads
    int n = gid & 15;
    int grp = gid >> 4;
    int d = grp % DINNER;
    int b = grp / DINNER;
    float A = -expf(A_log[d * NSTATE + n]);
    float Dv = Dp[d];
    float h = 0.f;
    int base = b * SEQ;
    for (int l = 0; l < SEQ; ++l) {
        int t = base + l;
        float dtv = dt[t * DINNER + d];
        float xv  = xs[t * DINNER + d];
        float Bv  = xdbl[t * 80 + DTRANK + n];
        float Cv  = xdbl[t * 80 + DTRANK + NSTATE + n];
        float dA = expf(dtv * A);
        h = fmaf(h, dA, dtv * Bv * xv);
        float p = h * Cv;
        p += __shfl_xor(p, 1, 16);
        p += __shfl_xor(p, 2, 16);
        p += __shfl_xor(p, 4, 16);
        p += __shfl_xor(p, 8, 16);
        if (n == 0) y[t * DINNER + d] = p + Dv * xv;
    }
}

// ---------------- gating: g = y * silu(z) ----------------
__global__ __launch_bounds__(256) void gate_kernel(const float* __restrict__ y,
                                                   const float* __restrict__ xz,
                                                   float* __restrict__ g) {
    int gid = blockIdx.x * 256 + threadIdx.x;  // over NTOK*DINNER
    int d = gid % DINNER;
    int t = gid / DINNER;
    if (t >= NTOK) return;
    float z = xz[t * (2 * DINNER) + DINNER + d];
    g[gid] = y[gid] * z / (1.f + expf(-z));
}

extern "C" void kernel_launch(void* const* d_in, const int* in_sizes, int n_in,
                              void* d_out, int out_size, void* d_ws, size_t ws_size,
                              hipStream_t stream) {
    const int*   tokens     = (const int*)d_in[0];
    const float* wte        = (const float*)d_in[1];
    const float* in_proj_w  = (const float*)d_in[2];   // (2, 3072, 768)
    const float* conv_w     = (const float*)d_in[3];   // (2, 1536, 1, 4)
    const float* conv_b     = (const float*)d_in[4];   // (2, 1536)
    const float* x_proj_w   = (const float*)d_in[5];   // (2, 80, 1536)
    const float* dt_proj_w  = (const float*)d_in[6];   // (2, 1536, 48)
    const float* dt_proj_b  = (const float*)d_in[7];   // (2, 1536)
    const float* out_proj_w = (const float*)d_in[8];   // (2, 768, 1536)
    const float* A_log      = (const float*)d_in[9];   // (2, 1536, 16)
    const float* Dparam     = (const float*)d_in[10];  // (2, 1536)
    const float* lm_head_w  = (const float*)d_in[11];  // (50304, 768)
    float* out = (float*)d_out;

    // fp32 workspace
    float* ws   = (float*)d_ws;
    float* x    = ws;                          // NTOK*DMODEL
    float* xn   = x    + NTOK * DMODEL;        // NTOK*DMODEL
    float* xz   = xn   + NTOK * DMODEL;        // NTOK*2*DINNER
    float* xs   = xz   + NTOK * 2 * DINNER;    // NTOK*DINNER
    float* xdbl = xs   + NTOK * DINNER;        // NTOK*80
    float* dtb  = xdbl + NTOK * 80;            // NTOK*DINNER
    float* yb   = dtb  + NTOK * DINNER;        // NTOK*DINNER
    // bf16 workspace (16B-aligned: fp32 region is a multiple of 16B)
    unsigned short* xnb   = (unsigned short*)(yb + NTOK * DINNER);
    unsigned short* gb    = xnb   + NTOK * DMODEL;
    unsigned short* inwb  = gb    + NTOK * DINNER;                 // 2*3072*768
    unsigned short* outwb = inwb  + 2 * 2 * DINNER * DMODEL;       // 2*768*1536
    unsigned short* lmwb  = outwb + 2 * DMODEL * DINNER;           // 50304*768

    // weight conversions (once per call)
    {
        int n8 = 2 * 2 * DINNER * DMODEL / 8;
        cvt_bf16_kernel<<<(n8 + 255) / 256, 256, 0, stream>>>(in_proj_w, inwb, n8);
        n8 = 2 * DMODEL * DINNER / 8;
        cvt_bf16_kernel<<<(n8 + 255) / 256, 256, 0, stream>>>(out_proj_w, outwb, n8);
        n8 = VOCAB * DMODEL / 8;
        cvt_bf16_kernel<<<(n8 + 255) / 256, 256, 0, stream>>>(lm_head_w, lmwb, n8);
    }

    // embed
    embed_kernel<<<NTOK * (DMODEL / 4) / 256, 256, 0, stream>>>(tokens, wte, x);

    for (int i = 0; i < NLAYER; ++i) {
        const unsigned short* inw = inwb + (size_t)i * 2 * DINNER * DMODEL;
        const float* cw   = conv_w     + (size_t)i * DINNER * 4;
        const float* cb   = conv_b     + (size_t)i * DINNER;
        const float* xpw  = x_proj_w   + (size_t)i * (DTRANK + 2 * NSTATE) * DINNER;
        const float* dtpw = dt_proj_w  + (size_t)i * DINNER * DTRANK;
        const float* dtpb = dt_proj_b  + (size_t)i * DINNER;
        const unsigned short* outw = outwb + (size_t)i * DMODEL * DINNER;
        const float* alog = A_log      + (size_t)i * DINNER * NSTATE;
        const float* dpar = Dparam     + (size_t)i * DINNER;

        rmsnorm_kernel<<<NTOK, 256, 0, stream>>>(x, xn);
        cvt_bf16_kernel<<<NTOK * DMODEL / 8 / 256, 256, 0, stream>>>(xn, xnb, NTOK * DMODEL / 8);
        // xz = xn @ in_w^T : (2048, 3072) [bf16 MFMA]
        gemm_bf16<0><<<dim3(2 * DINNER / 128, NTOK / 128), 256, 0, stream>>>(
            xnb, DMODEL, inw, DMODEL, xz, 2 * DINNER, DMODEL);
        // conv + silu -> xs
        conv_silu_kernel<<<NTOK * DINNER / 256, 256, 0, stream>>>(xz, cw, cb, xs);
        // x_dbl = xs @ xp_w^T : (2048, 80) [fp32]
        gemm_tn<0><<<dim3(2, NTOK / 64), 256, 0, stream>>>(
            xs, DINNER, xpw, DINNER, xdbl, 80, NTOK, 80, DINNER, nullptr);
        // dt = softplus(x_dbl[:, :48] @ dtp_w^T + b) : (2048, 1536) [fp32]
        gemm_tn<1><<<dim3(DINNER / 64, NTOK / 64), 256, 0, stream>>>(
            xdbl, 80, dtpw, DTRANK, dtb, DINNER, NTOK, DINNER, DTRANK, dtpb);
        // selective scan -> yb
        scan_kernel<<<BATCH * DINNER * NSTATE / 256, 256, 0, stream>>>(
            xs, dtb, xdbl, alog, dpar, yb);
        // g = yb * silu(z) -> xs (reuse), then bf16
        gate_kernel<<<NTOK * DINNER / 256, 256, 0, stream>>>(yb, xz, xs);
        cvt_bf16_kernel<<<NTOK * DINNER / 8 / 256, 256, 0, stream>>>(xs, gb, NTOK * DINNER / 8);
        // x += g @ out_w^T [bf16 MFMA, accumulate]
        gemm_bf16<2><<<dim3(DMODEL / 128, NTOK / 128), 256, 0, stream>>>(
            gb, DINNER, outw, DINNER, x, DMODEL, DINNER);
    }

    // final norm + lm_head [bf16 MFMA]
    rmsnorm_kernel<<<NTOK, 256, 0, stream>>>(x, xn);
    cvt_bf16_kernel<<<NTOK * DMODEL / 8 / 256, 256, 0, stream>>>(xn, xnb, NTOK * DMODEL / 8);
    gemm_bf16<0><<<dim3(VOCAB / 128, NTOK / 128), 256, 0, stream>>>(
        xnb, DMODEL, lmwb, DMODEL, out, VOCAB, DMODEL);
}

// Round 3
// 1402.470 us; speedup vs baseline: 3.2244x; 1.5558x over previous
//
#include <hip/hip_runtime.h>
#include <hip/hip_bf16.h>

#define BATCH 2
#define SEQ 1024
#define DMODEL 768
#define DINNER 1536
#define DTRANK 48
#define NSTATE 16
#define NLAYER 2
#define VOCAB 50304
#define NTOK (BATCH * SEQ)   // 2048

typedef __attribute__((ext_vector_type(8))) short short8;
typedef __attribute__((ext_vector_type(4))) float f32x4;

__device__ __forceinline__ unsigned short f2bf(float f) {
    union { float f; unsigned u; } v; v.f = f;
    unsigned r = v.u + 0x7fffu + ((v.u >> 16) & 1u);
    return (unsigned short)(r >> 16);
}

// ---------------- fp32 -> bf16 conversion (8 elems/thread) ----------------
__global__ __launch_bounds__(256) void cvt_bf16_kernel(const float* __restrict__ in,
                                                       unsigned short* __restrict__ out,
                                                       int n8) {
    int i = blockIdx.x * 256 + threadIdx.x;
    if (i >= n8) return;
    const float4* p = (const float4*)in + 2 * (size_t)i;
    float4 a = p[0], b = p[1];
    union { unsigned short us[8]; uint4 v; } o;
    o.us[0] = f2bf(a.x); o.us[1] = f2bf(a.y); o.us[2] = f2bf(a.z); o.us[3] = f2bf(a.w);
    o.us[4] = f2bf(b.x); o.us[5] = f2bf(b.y); o.us[6] = f2bf(b.z); o.us[7] = f2bf(b.w);
    ((uint4*)out)[i] = o.v;
}

// ---------------- bf16 MFMA GEMM: C[M,N] (+)= A[M,K] * B[N,K]^T ----------------
template <int EPI>
__global__ __launch_bounds__(256) void gemm_bf16(const unsigned short* __restrict__ A, int lda,
                                                 const unsigned short* __restrict__ B, int ldb,
                                                 float* __restrict__ C, int ldc,
                                                 int K) {
    __shared__ unsigned short As[128 * 32];
    __shared__ unsigned short Bs[128 * 32];
    const int tid = threadIdx.x;
    const int lane = tid & 63;
    const int wave = tid >> 6;
    const int m0 = blockIdx.y * 128;
    const int n0 = blockIdx.x * 128;
    const int wr = (wave >> 1) * 64;
    const int wc = (wave & 1) * 64;

    f32x4 acc[4][4] = {};

    for (int k0 = 0; k0 < K; k0 += 32) {
        __syncthreads();
        #pragma unroll
        for (int j = 0; j < 2; ++j) {
            int c = j * 256 + tid;
            int row = c >> 2;
            int kc = (c & 3) * 8;
            __builtin_amdgcn_global_load_lds(
                (const __attribute__((address_space(1))) unsigned int*)(A + (size_t)(m0 + row) * lda + k0 + kc),
                (__attribute__((address_space(3))) unsigned int*)(As + c * 8), 16, 0, 0);
            __builtin_amdgcn_global_load_lds(
                (const __attribute__((address_space(1))) unsigned int*)(B + (size_t)(n0 + row) * ldb + k0 + kc),
                (__attribute__((address_space(3))) unsigned int*)(Bs + c * 8), 16, 0, 0);
        }
        __syncthreads();

        short8 a[4], b[4];
        #pragma unroll
        for (int i = 0; i < 4; ++i)
            a[i] = *(const short8*)(As + (wr + i * 16 + (lane & 15)) * 32 + (lane >> 4) * 8);
        #pragma unroll
        for (int i = 0; i < 4; ++i)
            b[i] = *(const short8*)(Bs + (wc + i * 16 + (lane & 15)) * 32 + (lane >> 4) * 8);
        #pragma unroll
        for (int i = 0; i < 4; ++i)
            #pragma unroll
            for (int j = 0; j < 4; ++j)
                acc[i][j] = __builtin_amdgcn_mfma_f32_16x16x32_bf16(a[i], b[j], acc[i][j], 0, 0, 0);
    }

    const int row_base = m0 + wr + (lane >> 4) * 4;
    const int col_base = n0 + wc + (lane & 15);
    #pragma unroll
    for (int i = 0; i < 4; ++i)
        #pragma unroll
        for (int j = 0; j < 4; ++j)
            #pragma unroll
            for (int q = 0; q < 4; ++q) {
                size_t idx = (size_t)(row_base + i * 16 + q) * ldc + col_base + j * 16;
                if (EPI == 0) C[idx] = acc[i][j][q];
                else          C[idx] += acc[i][j][q];
            }
}

// ---------------- embedding gather ----------------
__global__ __launch_bounds__(256) void embed_kernel(const int* __restrict__ tokens,
                                                    const float* __restrict__ wte,
                                                    float* __restrict__ x) {
    int gid = blockIdx.x * 256 + threadIdx.x;
    int t = gid / (DMODEL / 4);
    int c = gid % (DMODEL / 4);
    if (t >= NTOK) return;
    int tok = tokens[t];
    ((float4*)x)[t * (DMODEL / 4) + c] = ((const float4*)wte)[(size_t)tok * (DMODEL / 4) + c];
}

// ---------------- RMSNorm (row = 768) ----------------
__global__ __launch_bounds__(256) void rmsnorm_kernel(const float* __restrict__ in,
                                                      float* __restrict__ out) {
    int row = blockIdx.x;
    int tid = threadIdx.x;
    const float* r = in + row * DMODEL;
    float v0 = r[tid], v1 = r[tid + 256], v2 = r[tid + 512];
    float s = v0 * v0 + v1 * v1 + v2 * v2;
    #pragma unroll
    for (int off = 32; off > 0; off >>= 1) s += __shfl_down(s, off);
    __shared__ float red[4];
    int wid = tid >> 6, lane = tid & 63;
    if (lane == 0) red[wid] = s;
    __syncthreads();
    if (tid == 0) {
        float tot = red[0] + red[1] + red[2] + red[3];
        red[0] = 1.0f / sqrtf(tot / (float)DMODEL + 1e-6f);
    }
    __syncthreads();
    float sc = red[0];
    float* o = out + row * DMODEL;
    o[tid] = v0 * sc; o[tid + 256] = v1 * sc; o[tid + 512] = v2 * sc;
}

// ---------------- fp32 GEMM (small shapes): C[M,N] = A[M,K]*B[N,K]^T ----------------
template <int EPI>
__global__ __launch_bounds__(256) void gemm_tn(const float* __restrict__ A, int lda,
                                               const float* __restrict__ B, int ldb,
                                               float* __restrict__ C, int ldc,
                                               int M, int N, int K,
                                               const float* __restrict__ bias) {
    __shared__ float As[16][68];
    __shared__ float Bs[16][68];
    const int tid = threadIdx.x;
    const int m0 = blockIdx.y * 64;
    const int n0 = blockIdx.x * 64;
    const int lr = tid >> 2;
    const int lq = (tid & 3) * 4;
    const int tm = (tid & 15) * 4;
    const int tn = (tid >> 4) * 4;
    float acc[4][4] = {};

    for (int k0 = 0; k0 < K; k0 += 16) {
        float4 av = *(const float4*)(A + (m0 + lr) * lda + k0 + lq);
        float4 bv = make_float4(0.f, 0.f, 0.f, 0.f);
        if (n0 + lr < N) bv = *(const float4*)(B + (n0 + lr) * ldb + k0 + lq);
        __syncthreads();
        As[lq + 0][lr] = av.x; As[lq + 1][lr] = av.y; As[lq + 2][lr] = av.z; As[lq + 3][lr] = av.w;
        Bs[lq + 0][lr] = bv.x; Bs[lq + 1][lr] = bv.y; Bs[lq + 2][lr] = bv.z; Bs[lq + 3][lr] = bv.w;
        __syncthreads();
        #pragma unroll
        for (int kk = 0; kk < 16; ++kk) {
            float4 a = *(const float4*)&As[kk][tm];
            float4 b = *(const float4*)&Bs[kk][tn];
            const float* ap = (const float*)&a;
            const float* bp = (const float*)&b;
            #pragma unroll
            for (int i = 0; i < 4; ++i)
                #pragma unroll
                for (int j = 0; j < 4; ++j)
                    acc[i][j] = fmaf(ap[i], bp[j], acc[i][j]);
        }
    }

    #pragma unroll
    for (int i = 0; i < 4; ++i) {
        int m = m0 + tm + i;
        #pragma unroll
        for (int j = 0; j < 4; ++j) {
            int n = n0 + tn + j;
            if (n >= N) continue;
            float v = acc[i][j];
            if (EPI == 0) {
                C[m * ldc + n] = v;
            } else {
                v += bias[n];
                C[m * ldc + n] = (v > 20.f) ? v : log1pf(expf(v));
            }
        }
    }
}

// ---------------- causal depthwise conv (D_CONV=4) + SiLU ----------------
__global__ __launch_bounds__(256) void conv_silu_kernel(const float* __restrict__ xz,
                                                        const float* __restrict__ cw,
                                                        const float* __restrict__ cb,
                                                        float* __restrict__ xs) {
    int gid = blockIdx.x * 256 + threadIdx.x;
    int d = gid % DINNER;
    int t = gid / DINNER;
    if (t >= NTOK) return;
    int l = t & (SEQ - 1);
    int tb = t - l;
    float4 w = ((const float4*)cw)[d];
    const float* wp = (const float*)&w;
    float acc = cb[d];
    #pragma unroll
    for (int k = 0; k < 4; ++k) {
        int lk = l - 3 + k;
        float v = (lk >= 0) ? xz[(tb + lk) * (2 * DINNER) + d] : 0.f;
        acc = fmaf(wp[k], v, acc);
    }
    xs[t * DINNER + d] = acc / (1.f + expf(-acc));
}

// ---------------- transpose dt,xs : [T][D] -> [B][D][L] (LDS 32x32 tiles) ----------------
__global__ __launch_bounds__(256) void transpose2_kernel(const float* __restrict__ dtb,
                                                         const float* __restrict__ xs,
                                                         float* __restrict__ dt_t,
                                                         float* __restrict__ xs_t) {
    __shared__ float t0[32][33];
    __shared__ float t1[32][33];
    const int tid = threadIdx.x;
    const int tx = tid & 31, ty = tid >> 5;          // ty 0..7
    const int tbase = blockIdx.x * 32;               // t
    const int dbase = blockIdx.y * 32;               // d
    #pragma unroll
    for (int i = 0; i < 4; ++i) {
        int t = tbase + ty + i * 8;
        t0[ty + i * 8][tx] = dtb[(size_t)t * DINNER + dbase + tx];
        t1[ty + i * 8][tx] = xs[(size_t)t * DINNER + dbase + tx];
    }
    __syncthreads();
    const int b = tbase >> 10;
    const int l0 = tbase & (SEQ - 1);
    #pragma unroll
    for (int i = 0; i < 4; ++i) {
        int d = dbase + ty + i * 8;
        size_t o = (size_t)(b * DINNER + d) * SEQ + l0 + tx;
        dt_t[o] = t0[tx][ty + i * 8];
        xs_t[o] = t1[tx][ty + i * 8];
    }
}

// ---------------- chunk-parallel selective scan ----------------
// grid: B*DINNER blocks; block 256 = 16 chunks x 16 states; chunk = 64 steps.
__global__ __launch_bounds__(256) void scan2_kernel(const float* __restrict__ dt_t,  // [B][D][L]
                                                    const float* __restrict__ x_t,   // [B][D][L]
                                                    const float* __restrict__ xdbl,  // [T][80]
                                                    const float* __restrict__ A_log, // [D][16]
                                                    const float* __restrict__ Dp,    // [D]
                                                    float* __restrict__ y_t) {       // [B][D][L]
    const int bd = blockIdx.x;
    const int d = bd % DINNER;
    const int b = bd / DINNER;
    const int tid = threadIdx.x;
    const int c = tid >> 4;          // chunk 0..15
    const int n = tid & 15;          // state 0..15

    const float* dtp = dt_t + (size_t)bd * SEQ + c * 64;
    const float* xp  = x_t  + (size_t)bd * SEQ + c * 64;
    const float* xd  = xdbl + (size_t)(b * SEQ + c * 64) * 80;
    const float A = -expf(A_log[d * NSTATE + n]);

    // phase 1: local chunk (a = prod dA, h = local state from 0)
    float a = 1.f, h = 0.f;
    #pragma unroll 4
    for (int q = 0; q < 16; ++q) {
        float4 dq = ((const float4*)dtp)[q];
        float4 xq = ((const float4*)xp)[q];
        const float* dv = (const float*)&dq;
        const float* xv = (const float*)&xq;
        #pragma unroll
        for (int j = 0; j < 4; ++j) {
            int l = q * 4 + j;
            float Bv = xd[l * 80 + DTRANK + n];
            float dA = expf(dv[j] * A);
            a *= dA;
            h = fmaf(h, dA, dv[j] * Bv * xv[j]);
        }
    }

    // phase 2: prefix combine across 16 chunks (per state n)
    __shared__ float sa[16][16];
    __shared__ float sb[16][16];
    sa[c][n] = a; sb[c][n] = h;
    __syncthreads();
    if (tid < 16) {
        float hrun = 0.f;
        #pragma unroll
        for (int cc = 0; cc < 16; ++cc) {
            float av = sa[cc][tid];
            float bv = sb[cc][tid];
            sa[cc][tid] = hrun;            // h-in for chunk cc
            hrun = fmaf(av, hrun, bv);
        }
    }
    __syncthreads();

    // phase 3: re-run chunk from incoming state, reduce over n, write y
    float hh = sa[c][n];
    const float Dv = Dp[d];
    float* yo = y_t + (size_t)bd * SEQ + c * 64;
    #pragma unroll 4
    for (int q = 0; q < 16; ++q) {
        float4 dq = ((const float4*)dtp)[q];
        float4 xq = ((const float4*)xp)[q];
        const float* dv = (const float*)&dq;
        const float* xv = (const float*)&xq;
        #pragma unroll
        for (int j = 0; j < 4; ++j) {
            int l = q * 4 + j;
            float Bv = xd[l * 80 + DTRANK + n];
            float Cv = xd[l * 80 + DTRANK + NSTATE + n];
            float dA = expf(dv[j] * A);
            hh = fmaf(hh, dA, dv[j] * Bv * xv[j]);
            float p = hh * Cv;
            p += __shfl_xor(p, 1, 16);
            p += __shfl_xor(p, 2, 16);
            p += __shfl_xor(p, 4, 16);
            p += __shfl_xor(p, 8, 16);
            if (n == 0) yo[l] = fmaf(Dv, xv[j], p);
        }
    }
}

// ---------------- fused gate + transpose + bf16: g[t][d] = y_t[b][d][l] * silu(z) ----------------
__global__ __launch_bounds__(256) void gate_tr_kernel(const float* __restrict__ y_t,
                                                      const float* __restrict__ xz,
                                                      unsigned short* __restrict__ g) {
    __shared__ float ty_[32][33];
    const int tid = threadIdx.x;
    const int tx = tid & 31, ty = tid >> 5;
    const int tbase = blockIdx.x * 32;
    const int dbase = blockIdx.y * 32;
    const int b = tbase >> 10;
    const int l0 = tbase & (SEQ - 1);
    #pragma unroll
    for (int i = 0; i < 4; ++i) {
        int d = dbase + ty + i * 8;
        ty_[ty + i * 8][tx] = y_t[(size_t)(b * DINNER + d) * SEQ + l0 + tx];
    }
    __syncthreads();
    #pragma unroll
    for (int i = 0; i < 4; ++i) {
        int t = tbase + ty + i * 8;
        int d = dbase + tx;
        float z = xz[(size_t)t * (2 * DINNER) + DINNER + d];
        float yv = ty_[tx][ty + i * 8];
        float gv = yv * z / (1.f + expf(-z));
        g[(size_t)t * DINNER + d] = f2bf(gv);
    }
}

extern "C" void kernel_launch(void* const* d_in, const int* in_sizes, int n_in,
                              void* d_out, int out_size, void* d_ws, size_t ws_size,
                              hipStream_t stream) {
    const int*   tokens     = (const int*)d_in[0];
    const float* wte        = (const float*)d_in[1];
    const float* in_proj_w  = (const float*)d_in[2];
    const float* conv_w     = (const float*)d_in[3];
    const float* conv_b     = (const float*)d_in[4];
    const float* x_proj_w   = (const float*)d_in[5];
    const float* dt_proj_w  = (const float*)d_in[6];
    const float* dt_proj_b  = (const float*)d_in[7];
    const float* out_proj_w = (const float*)d_in[8];
    const float* A_log      = (const float*)d_in[9];
    const float* Dparam     = (const float*)d_in[10];
    const float* lm_head_w  = (const float*)d_in[11];
    float* out = (float*)d_out;

    // fp32 workspace
    float* ws   = (float*)d_ws;
    float* x    = ws;                          // NTOK*DMODEL
    float* xn   = x    + NTOK * DMODEL;        // NTOK*DMODEL
    float* xz   = xn   + NTOK * DMODEL;        // NTOK*2*DINNER
    float* xs   = xz   + NTOK * 2 * DINNER;    // NTOK*DINNER
    float* xdbl = xs   + NTOK * DINNER;        // NTOK*80
    float* dtb  = xdbl + NTOK * 80;            // NTOK*DINNER
    float* dt_t = dtb  + NTOK * DINNER;        // NTOK*DINNER
    float* xs_t = dt_t + NTOK * DINNER;        // NTOK*DINNER
    float* y_t  = xs_t + NTOK * DINNER;        // NTOK*DINNER
    // bf16 workspace
    unsigned short* xnb   = (unsigned short*)(y_t + NTOK * DINNER);
    unsigned short* gb    = xnb   + NTOK * DMODEL;
    unsigned short* inwb  = gb    + NTOK * DINNER;
    unsigned short* outwb = inwb  + 2 * 2 * DINNER * DMODEL;
    unsigned short* lmwb  = outwb + 2 * DMODEL * DINNER;

    // weight conversions (once per call)
    {
        int n8 = 2 * 2 * DINNER * DMODEL / 8;
        cvt_bf16_kernel<<<(n8 + 255) / 256, 256, 0, stream>>>(in_proj_w, inwb, n8);
        n8 = 2 * DMODEL * DINNER / 8;
        cvt_bf16_kernel<<<(n8 + 255) / 256, 256, 0, stream>>>(out_proj_w, outwb, n8);
        n8 = VOCAB * DMODEL / 8;
        cvt_bf16_kernel<<<(n8 + 255) / 256, 256, 0, stream>>>(lm_head_w, lmwb, n8);
    }

    // embed
    embed_kernel<<<NTOK * (DMODEL / 4) / 256, 256, 0, stream>>>(tokens, wte, x);

    for (int i = 0; i < NLAYER; ++i) {
        const unsigned short* inw = inwb + (size_t)i * 2 * DINNER * DMODEL;
        const float* cw   = conv_w     + (size_t)i * DINNER * 4;
        const float* cb   = conv_b     + (size_t)i * DINNER;
        const float* xpw  = x_proj_w   + (size_t)i * (DTRANK + 2 * NSTATE) * DINNER;
        const float* dtpw = dt_proj_w  + (size_t)i * DINNER * DTRANK;
        const float* dtpb = dt_proj_b  + (size_t)i * DINNER;
        const unsigned short* outw = outwb + (size_t)i * DMODEL * DINNER;
        const float* alog = A_log      + (size_t)i * DINNER * NSTATE;
        const float* dpar = Dparam     + (size_t)i * DINNER;

        rmsnorm_kernel<<<NTOK, 256, 0, stream>>>(x, xn);
        cvt_bf16_kernel<<<NTOK * DMODEL / 8 / 256, 256, 0, stream>>>(xn, xnb, NTOK * DMODEL / 8);
        // xz = xn @ in_w^T : (2048, 3072) [bf16 MFMA]
        gemm_bf16<0><<<dim3(2 * DINNER / 128, NTOK / 128), 256, 0, stream>>>(
            xnb, DMODEL, inw, DMODEL, xz, 2 * DINNER, DMODEL);
        // conv + silu -> xs
        conv_silu_kernel<<<NTOK * DINNER / 256, 256, 0, stream>>>(xz, cw, cb, xs);
        // x_dbl = xs @ xp_w^T : (2048, 80) [fp32]
        gemm_tn<0><<<dim3(2, NTOK / 64), 256, 0, stream>>>(
            xs, DINNER, xpw, DINNER, xdbl, 80, NTOK, 80, DINNER, nullptr);
        // dt = softplus(x_dbl[:, :48] @ dtp_w^T + b) : (2048, 1536) [fp32]
        gemm_tn<1><<<dim3(DINNER / 64, NTOK / 64), 256, 0, stream>>>(
            xdbl, 80, dtpw, DTRANK, dtb, DINNER, NTOK, DINNER, DTRANK, dtpb);
        // transpose dt, xs -> [B][D][L]
        transpose2_kernel<<<dim3(NTOK / 32, DINNER / 32), 256, 0, stream>>>(dtb, xs, dt_t, xs_t);
        // chunk-parallel scan -> y_t [B][D][L]
        scan2_kernel<<<BATCH * DINNER, 256, 0, stream>>>(dt_t, xs_t, xdbl, alog, dpar, y_t);
        // fused gate + transpose back + bf16 -> gb [T][D]
        gate_tr_kernel<<<dim3(NTOK / 32, DINNER / 32), 256, 0, stream>>>(y_t, xz, gb);
        // x += g @ out_w^T [bf16 MFMA, accumulate]
        gemm_bf16<2><<<dim3(DMODEL / 128, NTOK / 128), 256, 0, stream>>>(
            gb, DINNER, outw, DINNER, x, DMODEL, DINNER);
    }

    // final norm + lm_head [bf16 MFMA]
    rmsnorm_kernel<<<NTOK, 256, 0, stream>>>(x, xn);
    cvt_bf16_kernel<<<NTOK * DMODEL / 8 / 256, 256, 0, stream>>>(xn, xnb, NTOK * DMODEL / 8);
    gemm_bf16<0><<<dim3(VOCAB / 128, NTOK / 128), 256, 0, stream>>>(
        xnb, DMODEL, lmwb, DMODEL, out, VOCAB, DMODEL);
}

// Round 6
// 1379.184 us; speedup vs baseline: 3.2788x; 1.0169x over previous
//
#include <hip/hip_runtime.h>
#include <hip/hip_bf16.h>

#define BATCH 2
#define SEQ 1024
#define DMODEL 768
#define DINNER 1536
#define DTRANK 48
#define NSTATE 16
#define NLAYER 2
#define VOCAB 50304
#define NTOK (BATCH * SEQ)   // 2048

typedef __attribute__((ext_vector_type(8))) short short8;
typedef __attribute__((ext_vector_type(4))) float f32x4;

__device__ __forceinline__ unsigned short f2bf(float f) {
    union { float f; unsigned u; } v; v.f = f;
    unsigned r = v.u + 0x7fffu + ((v.u >> 16) & 1u);
    return (unsigned short)(r >> 16);
}

// ---------------- fp32 -> bf16 conversion (8 elems/thread) ----------------
__global__ __launch_bounds__(256) void cvt_bf16_kernel(const float* __restrict__ in,
                                                       unsigned short* __restrict__ out,
                                                       int n8) {
    int i = blockIdx.x * 256 + threadIdx.x;
    if (i >= n8) return;
    const float4* p = (const float4*)in + 2 * (size_t)i;
    float4 a = p[0], b = p[1];
    union { unsigned short us[8]; uint4 v; } o;
    o.us[0] = f2bf(a.x); o.us[1] = f2bf(a.y); o.us[2] = f2bf(a.z); o.us[3] = f2bf(a.w);
    o.us[4] = f2bf(b.x); o.us[5] = f2bf(b.y); o.us[6] = f2bf(b.z); o.us[7] = f2bf(b.w);
    ((uint4*)out)[i] = o.v;
}

// ---------------- bf16 MFMA GEMM: C[M,N] (+)= A[M,K] * B[N,K]^T ----------------
// m97 structure + m204 bijective XCD panel-chunk swizzle.
// 1-D grid of (M/128)*(N/128) blocks; tile id = n_tile*mtiles + m_tile
// (m fastest => B-panel sharers consecutive => same XCD after chunking).
template <int EPI>
__global__ __launch_bounds__(256) void gemm_bf16(const unsigned short* __restrict__ A, int lda,
                                                 const unsigned short* __restrict__ B, int ldb,
                                                 float* __restrict__ C, int ldc,
                                                 int K, int mtiles) {
    // bijective XCD swizzle (m204): orig round-robin pos -> chunked pos
    const int nwg = gridDim.x;
    const int bid = blockIdx.x;
    const int q = nwg >> 3, r = nwg & 7;
    const int xcd = bid & 7, loc = bid >> 3;
    const int wgid = (xcd < r ? xcd * (q + 1) : r * (q + 1) + (xcd - r) * q) + loc;
    const int m0 = (wgid % mtiles) * 128;
    const int n0 = (wgid / mtiles) * 128;

    __shared__ unsigned short As[128 * 32];
    __shared__ unsigned short Bs[128 * 32];
    const int tid = threadIdx.x;
    const int lane = tid & 63;
    const int wave = tid >> 6;
    const int wr = (wave >> 1) * 64;
    const int wc = (wave & 1) * 64;

    f32x4 acc[4][4] = {};

    for (int k0 = 0; k0 < K; k0 += 32) {
        __syncthreads();
        #pragma unroll
        for (int j = 0; j < 2; ++j) {
            int c = j * 256 + tid;
            int row = c >> 2;
            int kc = (c & 3) * 8;
            __builtin_amdgcn_global_load_lds(
                (const __attribute__((address_space(1))) unsigned int*)(A + (size_t)(m0 + row) * lda + k0 + kc),
                (__attribute__((address_space(3))) unsigned int*)(As + c * 8), 16, 0, 0);
            __builtin_amdgcn_global_load_lds(
                (const __attribute__((address_space(1))) unsigned int*)(B + (size_t)(n0 + row) * ldb + k0 + kc),
                (__attribute__((address_space(3))) unsigned int*)(Bs + c * 8), 16, 0, 0);
        }
        __syncthreads();

        short8 a[4], b[4];
        #pragma unroll
        for (int i = 0; i < 4; ++i)
            a[i] = *(const short8*)(As + (wr + i * 16 + (lane & 15)) * 32 + (lane >> 4) * 8);
        #pragma unroll
        for (int i = 0; i < 4; ++i)
            b[i] = *(const short8*)(Bs + (wc + i * 16 + (lane & 15)) * 32 + (lane >> 4) * 8);
        #pragma unroll
        for (int i = 0; i < 4; ++i)
            #pragma unroll
            for (int j = 0; j < 4; ++j)
                acc[i][j] = __builtin_amdgcn_mfma_f32_16x16x32_bf16(a[i], b[j], acc[i][j], 0, 0, 0);
    }

    const int row_base = m0 + wr + (lane >> 4) * 4;
    const int col_base = n0 + wc + (lane & 15);
    #pragma unroll
    for (int i = 0; i < 4; ++i)
        #pragma unroll
        for (int j = 0; j < 4; ++j)
            #pragma unroll
            for (int q2 = 0; q2 < 4; ++q2) {
                size_t idx = (size_t)(row_base + i * 16 + q2) * ldc + col_base + j * 16;
                if (EPI == 0) C[idx] = acc[i][j][q2];
                else          C[idx] += acc[i][j][q2];
            }
}

// ---------------- embedding gather ----------------
__global__ __launch_bounds__(256) void embed_kernel(const int* __restrict__ tokens,
                                                    const float* __restrict__ wte,
                                                    float* __restrict__ x) {
    int gid = blockIdx.x * 256 + threadIdx.x;
    int t = gid / (DMODEL / 4);
    int c = gid % (DMODEL / 4);
    if (t >= NTOK) return;
    int tok = tokens[t];
    ((float4*)x)[t * (DMODEL / 4) + c] = ((const float4*)wte)[(size_t)tok * (DMODEL / 4) + c];
}

// ---------------- RMSNorm (row = 768) -> bf16 out ----------------
__global__ __launch_bounds__(256) void rmsnorm_bf16_kernel(const float* __restrict__ in,
                                                           unsigned short* __restrict__ out) {
    int row = blockIdx.x;
    int tid = threadIdx.x;
    const float* r = in + row * DMODEL;
    float v0 = r[tid], v1 = r[tid + 256], v2 = r[tid + 512];
    float s = v0 * v0 + v1 * v1 + v2 * v2;
    #pragma unroll
    for (int off = 32; off > 0; off >>= 1) s += __shfl_down(s, off);
    __shared__ float red[4];
    int wid = tid >> 6, lane = tid & 63;
    if (lane == 0) red[wid] = s;
    __syncthreads();
    if (tid == 0) {
        float tot = red[0] + red[1] + red[2] + red[3];
        red[0] = 1.0f / sqrtf(tot / (float)DMODEL + 1e-6f);
    }
    __syncthreads();
    float sc = red[0];
    unsigned short* o = out + row * DMODEL;
    o[tid] = f2bf(v0 * sc); o[tid + 256] = f2bf(v1 * sc); o[tid + 512] = f2bf(v2 * sc);
}

// ---------------- fp32 GEMM (small shapes): C[M,N] = A[M,K]*B[N,K]^T ----------------
template <int EPI>
__global__ __launch_bounds__(256) void gemm_tn(const float* __restrict__ A, int lda,
                                               const float* __restrict__ B, int ldb,
                                               float* __restrict__ C, int ldc,
                                               int M, int N, int K,
                                               const float* __restrict__ bias) {
    __shared__ float As[16][68];
    __shared__ float Bs[16][68];
    const int tid = threadIdx.x;
    const int m0 = blockIdx.y * 64;
    const int n0 = blockIdx.x * 64;
    const int lr = tid >> 2;
    const int lq = (tid & 3) * 4;
    const int tm = (tid & 15) * 4;
    const int tn = (tid >> 4) * 4;
    float acc[4][4] = {};

    for (int k0 = 0; k0 < K; k0 += 16) {
        float4 av = *(const float4*)(A + (m0 + lr) * lda + k0 + lq);
        float4 bv = make_float4(0.f, 0.f, 0.f, 0.f);
        if (n0 + lr < N) bv = *(const float4*)(B + (n0 + lr) * ldb + k0 + lq);
        __syncthreads();
        As[lq + 0][lr] = av.x; As[lq + 1][lr] = av.y; As[lq + 2][lr] = av.z; As[lq + 3][lr] = av.w;
        Bs[lq + 0][lr] = bv.x; Bs[lq + 1][lr] = bv.y; Bs[lq + 2][lr] = bv.z; Bs[lq + 3][lr] = bv.w;
        __syncthreads();
        #pragma unroll
        for (int kk = 0; kk < 16; ++kk) {
            float4 a = *(const float4*)&As[kk][tm];
            float4 b = *(const float4*)&Bs[kk][tn];
            const float* ap = (const float*)&a;
            const float* bp = (const float*)&b;
            #pragma unroll
            for (int i = 0; i < 4; ++i)
                #pragma unroll
                for (int j = 0; j < 4; ++j)
                    acc[i][j] = fmaf(ap[i], bp[j], acc[i][j]);
        }
    }

    #pragma unroll
    for (int i = 0; i < 4; ++i) {
        int m = m0 + tm + i;
        #pragma unroll
        for (int j = 0; j < 4; ++j) {
            int n = n0 + tn + j;
            if (n >= N) continue;
            float v = acc[i][j];
            if (EPI == 0) {
                C[m * ldc + n] = v;
            } else {
                v += bias[n];
                C[m * ldc + n] = (v > 20.f) ? v : log1pf(expf(v));
            }
        }
    }
}

// ---------------- causal depthwise conv (D_CONV=4) + SiLU ----------------
__global__ __launch_bounds__(256) void conv_silu_kernel(const float* __restrict__ xz,
                                                        const float* __restrict__ cw,
                                                        const float* __restrict__ cb,
                                                        float* __restrict__ xs) {
    int gid = blockIdx.x * 256 + threadIdx.x;
    int d = gid % DINNER;
    int t = gid / DINNER;
    if (t >= NTOK) return;
    int l = t & (SEQ - 1);
    int tb = t - l;
    float4 w = ((const float4*)cw)[d];
    const float* wp = (const float*)&w;
    float acc = cb[d];
    #pragma unroll
    for (int k = 0; k < 4; ++k) {
        int lk = l - 3 + k;
        float v = (lk >= 0) ? xz[(tb + lk) * (2 * DINNER) + d] : 0.f;
        acc = fmaf(wp[k], v, acc);
    }
    xs[t * DINNER + d] = acc / (1.f + expf(-acc));
}

// ---------------- transpose dt,xs : [T][D] -> [B][D][L] (LDS 32x32 tiles) ----------------
__global__ __launch_bounds__(256) void transpose2_kernel(const float* __restrict__ dtb,
                                                         const float* __restrict__ xs,
                                                         float* __restrict__ dt_t,
                                                         float* __restrict__ xs_t) {
    __shared__ float t0[32][33];
    __shared__ float t1[32][33];
    const int tid = threadIdx.x;
    const int tx = tid & 31, ty = tid >> 5;
    const int tbase = blockIdx.x * 32;
    const int dbase = blockIdx.y * 32;
    #pragma unroll
    for (int i = 0; i < 4; ++i) {
        int t = tbase + ty + i * 8;
        t0[ty + i * 8][tx] = dtb[(size_t)t * DINNER + dbase + tx];
        t1[ty + i * 8][tx] = xs[(size_t)t * DINNER + dbase + tx];
    }
    __syncthreads();
    const int b = tbase >> 10;
    const int l0 = tbase & (SEQ - 1);
    #pragma unroll
    for (int i = 0; i < 4; ++i) {
        int d = dbase + ty + i * 8;
        size_t o = (size_t)(b * DINNER + d) * SEQ + l0 + tx;
        dt_t[o] = t0[tx][ty + i * 8];
        xs_t[o] = t1[tx][ty + i * 8];
    }
}

// ---------------- chunk-parallel selective scan ----------------
__global__ __launch_bounds__(256) void scan2_kernel(const float* __restrict__ dt_t,
                                                    const float* __restrict__ x_t,
                                                    const float* __restrict__ xdbl,
                                                    const float* __restrict__ A_log,
                                                    const float* __restrict__ Dp,
                                                    float* __restrict__ y_t) {
    const int bd = blockIdx.x;
    const int d = bd % DINNER;
    const int b = bd / DINNER;
    const int tid = threadIdx.x;
    const int c = tid >> 4;
    const int n = tid & 15;

    const float* dtp = dt_t + (size_t)bd * SEQ + c * 64;
    const float* xp  = x_t  + (size_t)bd * SEQ + c * 64;
    const float* xd  = xdbl + (size_t)(b * SEQ + c * 64) * 80;
    const float A = -expf(A_log[d * NSTATE + n]);

    float a = 1.f, h = 0.f;
    #pragma unroll 4
    for (int qq = 0; qq < 16; ++qq) {
        float4 dq = ((const float4*)dtp)[qq];
        float4 xq = ((const float4*)xp)[qq];
        const float* dv = (const float*)&dq;
        const float* xv = (const float*)&xq;
        #pragma unroll
        for (int j = 0; j < 4; ++j) {
            int l = qq * 4 + j;
            float Bv = xd[l * 80 + DTRANK + n];
            float dA = expf(dv[j] * A);
            a *= dA;
            h = fmaf(h, dA, dv[j] * Bv * xv[j]);
        }
    }

    __shared__ float sa[16][16];
    __shared__ float sb[16][16];
    sa[c][n] = a; sb[c][n] = h;
    __syncthreads();
    if (tid < 16) {
        float hrun = 0.f;
        #pragma unroll
        for (int cc = 0; cc < 16; ++cc) {
            float av = sa[cc][tid];
            float bv = sb[cc][tid];
            sa[cc][tid] = hrun;
            hrun = fmaf(av, hrun, bv);
        }
    }
    __syncthreads();

    float hh = sa[c][n];
    const float Dv = Dp[d];
    float* yo = y_t + (size_t)bd * SEQ + c * 64;
    #pragma unroll 4
    for (int qq = 0; qq < 16; ++qq) {
        float4 dq = ((const float4*)dtp)[qq];
        float4 xq = ((const float4*)xp)[qq];
        const float* dv = (const float*)&dq;
        const float* xv = (const float*)&xq;
        #pragma unroll
        for (int j = 0; j < 4; ++j) {
            int l = qq * 4 + j;
            float Bv = xd[l * 80 + DTRANK + n];
            float Cv = xd[l * 80 + DTRANK + NSTATE + n];
            float dA = expf(dv[j] * A);
            hh = fmaf(hh, dA, dv[j] * Bv * xv[j]);
            float p = hh * Cv;
            p += __shfl_xor(p, 1, 16);
            p += __shfl_xor(p, 2, 16);
            p += __shfl_xor(p, 4, 16);
            p += __shfl_xor(p, 8, 16);
            if (n == 0) yo[l] = fmaf(Dv, xv[j], p);
        }
    }
}

// ---------------- fused gate + transpose + bf16 ----------------
__global__ __launch_bounds__(256) void gate_tr_kernel(const float* __restrict__ y_t,
                                                      const float* __restrict__ xz,
                                                      unsigned short* __restrict__ g) {
    __shared__ float ty_[32][33];
    const int tid = threadIdx.x;
    const int tx = tid & 31, ty = tid >> 5;
    const int tbase = blockIdx.x * 32;
    const int dbase = blockIdx.y * 32;
    const int b = tbase >> 10;
    const int l0 = tbase & (SEQ - 1);
    #pragma unroll
    for (int i = 0; i < 4; ++i) {
        int d = dbase + ty + i * 8;
        ty_[ty + i * 8][tx] = y_t[(size_t)(b * DINNER + d) * SEQ + l0 + tx];
    }
    __syncthreads();
    #pragma unroll
    for (int i = 0; i < 4; ++i) {
        int t = tbase + ty + i * 8;
        int d = dbase + tx;
        float z = xz[(size_t)t * (2 * DINNER) + DINNER + d];
        float yv = ty_[tx][ty + i * 8];
        float gv = yv * z / (1.f + expf(-z));
        g[(size_t)t * DINNER + d] = f2bf(gv);
    }
}

extern "C" void kernel_launch(void* const* d_in, const int* in_sizes, int n_in,
                              void* d_out, int out_size, void* d_ws, size_t ws_size,
                              hipStream_t stream) {
    const int*   tokens     = (const int*)d_in[0];
    const float* wte        = (const float*)d_in[1];
    const float* in_proj_w  = (const float*)d_in[2];
    const float* conv_w     = (const float*)d_in[3];
    const float* conv_b     = (const float*)d_in[4];
    const float* x_proj_w   = (const float*)d_in[5];
    const float* dt_proj_w  = (const float*)d_in[6];
    const float* dt_proj_b  = (const float*)d_in[7];
    const float* out_proj_w = (const float*)d_in[8];
    const float* A_log      = (const float*)d_in[9];
    const float* Dparam     = (const float*)d_in[10];
    const float* lm_head_w  = (const float*)d_in[11];
    float* out = (float*)d_out;

    // fp32 workspace
    float* ws   = (float*)d_ws;
    float* x    = ws;                          // NTOK*DMODEL
    float* xz   = x    + NTOK * DMODEL;        // NTOK*2*DINNER
    float* xs   = xz   + NTOK * 2 * DINNER;    // NTOK*DINNER
    float* xdbl = xs   + NTOK * DINNER;        // NTOK*80
    float* dtb  = xdbl + NTOK * 80;            // NTOK*DINNER
    float* dt_t = dtb  + NTOK * DINNER;        // NTOK*DINNER
    float* xs_t = dt_t + NTOK * DINNER;        // NTOK*DINNER
    float* y_t  = xs_t + NTOK * DINNER;        // NTOK*DINNER
    // bf16 workspace
    unsigned short* xnb   = (unsigned short*)(y_t + NTOK * DINNER);
    unsigned short* gb    = xnb   + NTOK * DMODEL;
    unsigned short* inwb  = gb    + NTOK * DINNER;
    unsigned short* outwb = inwb  + 2 * 2 * DINNER * DMODEL;
    unsigned short* lmwb  = outwb + 2 * DMODEL * DINNER;

    // weight conversions (once per call)
    {
        int n8 = 2 * 2 * DINNER * DMODEL / 8;
        cvt_bf16_kernel<<<(n8 + 255) / 256, 256, 0, stream>>>(in_proj_w, inwb, n8);
        n8 = 2 * DMODEL * DINNER / 8;
        cvt_bf16_kernel<<<(n8 + 255) / 256, 256, 0, stream>>>(out_proj_w, outwb, n8);
        n8 = VOCAB * DMODEL / 8;
        cvt_bf16_kernel<<<(n8 + 255) / 256, 256, 0, stream>>>(lm_head_w, lmwb, n8);
    }

    // embed
    embed_kernel<<<NTOK * (DMODEL / 4) / 256, 256, 0, stream>>>(tokens, wte, x);

    for (int i = 0; i < NLAYER; ++i) {
        const unsigned short* inw = inwb + (size_t)i * 2 * DINNER * DMODEL;
        const float* cw   = conv_w     + (size_t)i * DINNER * 4;
        const float* cb   = conv_b     + (size_t)i * DINNER;
        const float* xpw  = x_proj_w   + (size_t)i * (DTRANK + 2 * NSTATE) * DINNER;
        const float* dtpw = dt_proj_w  + (size_t)i * DINNER * DTRANK;
        const float* dtpb = dt_proj_b  + (size_t)i * DINNER;
        const unsigned short* outw = outwb + (size_t)i * DMODEL * DINNER;
        const float* alog = A_log      + (size_t)i * DINNER * NSTATE;
        const float* dpar = Dparam     + (size_t)i * DINNER;

        // rmsnorm -> bf16 directly
        rmsnorm_bf16_kernel<<<NTOK, 256, 0, stream>>>(x, xnb);
        // xz = xn @ in_w^T : (2048, 3072) [bf16 MFMA, XCD-swizzled]
        gemm_bf16<0><<<(NTOK / 128) * (2 * DINNER / 128), 256, 0, stream>>>(
            xnb, DMODEL, inw, DMODEL, xz, 2 * DINNER, DMODEL, NTOK / 128);
        // conv + silu -> xs
        conv_silu_kernel<<<NTOK * DINNER / 256, 256, 0, stream>>>(xz, cw, cb, xs);
        // x_dbl = xs @ xp_w^T : (2048, 80) [fp32]
        gemm_tn<0><<<dim3(2, NTOK / 64), 256, 0, stream>>>(
            xs, DINNER, xpw, DINNER, xdbl, 80, NTOK, 80, DINNER, nullptr);
        // dt = softplus(x_dbl[:, :48] @ dtp_w^T + b) : (2048, 1536) [fp32]
        gemm_tn<1><<<dim3(DINNER / 64, NTOK / 64), 256, 0, stream>>>(
            xdbl, 80, dtpw, DTRANK, dtb, DINNER, NTOK, DINNER, DTRANK, dtpb);
        // transpose dt, xs -> [B][D][L]
        transpose2_kernel<<<dim3(NTOK / 32, DINNER / 32), 256, 0, stream>>>(dtb, xs, dt_t, xs_t);
        // chunk-parallel scan -> y_t [B][D][L]
        scan2_kernel<<<BATCH * DINNER, 256, 0, stream>>>(dt_t, xs_t, xdbl, alog, dpar, y_t);
        // fused gate + transpose back + bf16 -> gb [T][D]
        gate_tr_kernel<<<dim3(NTOK / 32, DINNER / 32), 256, 0, stream>>>(y_t, xz, gb);
        // x += g @ out_w^T [bf16 MFMA, accumulate, XCD-swizzled]
        gemm_bf16<2><<<(NTOK / 128) * (DMODEL / 128), 256, 0, stream>>>(
            gb, DINNER, outw, DINNER, x, DMODEL, DINNER, NTOK / 128);
    }

    // final norm + lm_head [bf16 MFMA, XCD-swizzled]
    rmsnorm_bf16_kernel<<<NTOK, 256, 0, stream>>>(x, xnb);
    gemm_bf16<0><<<(NTOK / 128) * (VOCAB / 128), 256, 0, stream>>>(
        xnb, DMODEL, lmwb, DMODEL, out, VOCAB, DMODEL, NTOK / 128);
}

// Round 8
// 1319.075 us; speedup vs baseline: 3.4282x; 1.0456x over previous
//
#include <hip/hip_runtime.h>
#include <hip/hip_bf16.h>

#define BATCH 2
#define SEQ 1024
#define DMODEL 768
#define DINNER 1536
#define DTRANK 48
#define NSTATE 16
#define NLAYER 2
#define VOCAB 50304
#define NTOK (BATCH * SEQ)   // 2048

typedef __attribute__((ext_vector_type(8))) short short8;
typedef __attribute__((ext_vector_type(4))) float f32x4;

__device__ __forceinline__ unsigned short f2bf(float f) {
    union { float f; unsigned u; } v; v.f = f;
    unsigned r = v.u + 0x7fffu + ((v.u >> 16) & 1u);
    return (unsigned short)(r >> 16);
}

// ---------------- fp32 -> bf16 conversion (8 elems/thread) ----------------
__global__ __launch_bounds__(256) void cvt_bf16_kernel(const float* __restrict__ in,
                                                       unsigned short* __restrict__ out,
                                                       int n8) {
    int i = blockIdx.x * 256 + threadIdx.x;
    if (i >= n8) return;
    const float4* p = (const float4*)in + 2 * (size_t)i;
    float4 a = p[0], b = p[1];
    union { unsigned short us[8]; uint4 v; } o;
    o.us[0] = f2bf(a.x); o.us[1] = f2bf(a.y); o.us[2] = f2bf(a.z); o.us[3] = f2bf(a.w);
    o.us[4] = f2bf(b.x); o.us[5] = f2bf(b.y); o.us[6] = f2bf(b.z); o.us[7] = f2bf(b.w);
    ((uint4*)out)[i] = o.v;
}

// ---------------- 128x128 bf16 MFMA GEMM: C[M,N] = A[M,K] * B[N,K]^T (fp32 store) ----------------
// m97 structure + m204 bijective XCD panel-chunk swizzle (1-D grid, m-tile fastest).
__global__ __launch_bounds__(256) void gemm_bf16(const unsigned short* __restrict__ A, int lda,
                                                 const unsigned short* __restrict__ B, int ldb,
                                                 float* __restrict__ C, int ldc,
                                                 int K, int mtiles) {
    const int nwg = gridDim.x;
    const int bid = blockIdx.x;
    const int q = nwg >> 3, r = nwg & 7;
    const int xcd = bid & 7, loc = bid >> 3;
    const int wgid = (xcd < r ? xcd * (q + 1) : r * (q + 1) + (xcd - r) * q) + loc;
    const int m0 = (wgid % mtiles) * 128;
    const int n0 = (wgid / mtiles) * 128;

    __shared__ unsigned short As[128 * 32];
    __shared__ unsigned short Bs[128 * 32];
    const int tid = threadIdx.x;
    const int lane = tid & 63;
    const int wave = tid >> 6;
    const int wr = (wave >> 1) * 64;
    const int wc = (wave & 1) * 64;

    f32x4 acc[4][4] = {};

    for (int k0 = 0; k0 < K; k0 += 32) {
        __syncthreads();
        #pragma unroll
        for (int j = 0; j < 2; ++j) {
            int c = j * 256 + tid;
            int row = c >> 2;
            int kc = (c & 3) * 8;
            __builtin_amdgcn_global_load_lds(
                (const __attribute__((address_space(1))) unsigned int*)(A + (size_t)(m0 + row) * lda + k0 + kc),
                (__attribute__((address_space(3))) unsigned int*)(As + c * 8), 16, 0, 0);
            __builtin_amdgcn_global_load_lds(
                (const __attribute__((address_space(1))) unsigned int*)(B + (size_t)(n0 + row) * ldb + k0 + kc),
                (__attribute__((address_space(3))) unsigned int*)(Bs + c * 8), 16, 0, 0);
        }
        __syncthreads();

        short8 a[4], b[4];
        #pragma unroll
        for (int i = 0; i < 4; ++i)
            a[i] = *(const short8*)(As + (wr + i * 16 + (lane & 15)) * 32 + (lane >> 4) * 8);
        #pragma unroll
        for (int i = 0; i < 4; ++i)
            b[i] = *(const short8*)(Bs + (wc + i * 16 + (lane & 15)) * 32 + (lane >> 4) * 8);
        #pragma unroll
        for (int i = 0; i < 4; ++i)
            #pragma unroll
            for (int j = 0; j < 4; ++j)
                acc[i][j] = __builtin_amdgcn_mfma_f32_16x16x32_bf16(a[i], b[j], acc[i][j], 0, 0, 0);
    }

    const int row_base = m0 + wr + (lane >> 4) * 4;
    const int col_base = n0 + wc + (lane & 15);
    #pragma unroll
    for (int i = 0; i < 4; ++i)
        #pragma unroll
        for (int j = 0; j < 4; ++j)
            #pragma unroll
            for (int q2 = 0; q2 < 4; ++q2) {
                size_t idx = (size_t)(row_base + i * 16 + q2) * ldc + col_base + j * 16;
                C[idx] = acc[i][j][q2];
            }
}

// ---------------- 64x64 bf16 MFMA GEMM (high-occupancy variant for small-N GEMMs) ----------------
// EPI: 1 = bias + softplus -> fp32, 2 = fp32 accumulate, 3 = bf16 store
template <int EPI>
__global__ __launch_bounds__(256) void gemm64(const unsigned short* __restrict__ A, int lda,
                                              const unsigned short* __restrict__ B, int ldb,
                                              void* __restrict__ Cp, int ldc,
                                              int K, int mtiles,
                                              const float* __restrict__ bias) {
    const int nwg = gridDim.x;
    const int bid = blockIdx.x;
    const int q = nwg >> 3, r = nwg & 7;
    const int xcd = bid & 7, loc = bid >> 3;
    const int wgid = (xcd < r ? xcd * (q + 1) : r * (q + 1) + (xcd - r) * q) + loc;
    const int m0 = (wgid % mtiles) * 64;
    const int n0 = (wgid / mtiles) * 64;

    __shared__ unsigned short As[64 * 32];
    __shared__ unsigned short Bs[64 * 32];
    const int tid = threadIdx.x;
    const int lane = tid & 63;
    const int wave = tid >> 6;
    const int wr = (wave >> 1) * 32;
    const int wc = (wave & 1) * 32;
    const int srow = tid >> 2;
    const int skc = (tid & 3) * 8;

    f32x4 acc[2][2] = {};

    for (int k0 = 0; k0 < K; k0 += 32) {
        __syncthreads();
        __builtin_amdgcn_global_load_lds(
            (const __attribute__((address_space(1))) unsigned int*)(A + (size_t)(m0 + srow) * lda + k0 + skc),
            (__attribute__((address_space(3))) unsigned int*)(As + tid * 8), 16, 0, 0);
        __builtin_amdgcn_global_load_lds(
            (const __attribute__((address_space(1))) unsigned int*)(B + (size_t)(n0 + srow) * ldb + k0 + skc),
            (__attribute__((address_space(3))) unsigned int*)(Bs + tid * 8), 16, 0, 0);
        __syncthreads();

        short8 a[2], b[2];
        #pragma unroll
        for (int i = 0; i < 2; ++i)
            a[i] = *(const short8*)(As + (wr + i * 16 + (lane & 15)) * 32 + (lane >> 4) * 8);
        #pragma unroll
        for (int i = 0; i < 2; ++i)
            b[i] = *(const short8*)(Bs + (wc + i * 16 + (lane & 15)) * 32 + (lane >> 4) * 8);
        #pragma unroll
        for (int i = 0; i < 2; ++i)
            #pragma unroll
            for (int j = 0; j < 2; ++j)
                acc[i][j] = __builtin_amdgcn_mfma_f32_16x16x32_bf16(a[i], b[j], acc[i][j], 0, 0, 0);
    }

    const int row_base = m0 + wr + (lane >> 4) * 4;
    const int col_base = n0 + wc + (lane & 15);
    #pragma unroll
    for (int i = 0; i < 2; ++i)
        #pragma unroll
        for (int j = 0; j < 2; ++j)
            #pragma unroll
            for (int q2 = 0; q2 < 4; ++q2) {
                int rowg = row_base + i * 16 + q2;
                int colg = col_base + j * 16;
                size_t idx = (size_t)rowg * ldc + colg;
                float v = acc[i][j][q2];
                if (EPI == 1) {
                    v += bias[colg];
                    ((float*)Cp)[idx] = (v > 20.f) ? v : log1pf(expf(v));
                } else if (EPI == 2) {
                    ((float*)Cp)[idx] += v;
                } else {
                    ((unsigned short*)Cp)[idx] = f2bf(v);
                }
            }
}

// ---------------- embedding gather ----------------
__global__ __launch_bounds__(256) void embed_kernel(const int* __restrict__ tokens,
                                                    const float* __restrict__ wte,
                                                    float* __restrict__ x) {
    int gid = blockIdx.x * 256 + threadIdx.x;
    int t = gid / (DMODEL / 4);
    int c = gid % (DMODEL / 4);
    if (t >= NTOK) return;
    int tok = tokens[t];
    ((float4*)x)[t * (DMODEL / 4) + c] = ((const float4*)wte)[(size_t)tok * (DMODEL / 4) + c];
}

// ---------------- RMSNorm (row = 768) -> bf16 out ----------------
__global__ __launch_bounds__(256) void rmsnorm_bf16_kernel(const float* __restrict__ in,
                                                           unsigned short* __restrict__ out) {
    int row = blockIdx.x;
    int tid = threadIdx.x;
    const float* r = in + row * DMODEL;
    float v0 = r[tid], v1 = r[tid + 256], v2 = r[tid + 512];
    float s = v0 * v0 + v1 * v1 + v2 * v2;
    #pragma unroll
    for (int off = 32; off > 0; off >>= 1) s += __shfl_down(s, off);
    __shared__ float red[4];
    int wid = tid >> 6, lane = tid & 63;
    if (lane == 0) red[wid] = s;
    __syncthreads();
    if (tid == 0) {
        float tot = red[0] + red[1] + red[2] + red[3];
        red[0] = 1.0f / sqrtf(tot / (float)DMODEL + 1e-6f);
    }
    __syncthreads();
    float sc = red[0];
    unsigned short* o = out + row * DMODEL;
    o[tid] = f2bf(v0 * sc); o[tid + 256] = f2bf(v1 * sc); o[tid + 512] = f2bf(v2 * sc);
}

// ---------------- causal depthwise conv (D_CONV=4) + SiLU -> fp32 + bf16 ----------------
__global__ __launch_bounds__(256) void conv_silu_kernel(const float* __restrict__ xz,
                                                        const float* __restrict__ cw,
                                                        const float* __restrict__ cb,
                                                        float* __restrict__ xs,
                                                        unsigned short* __restrict__ xsb) {
    int gid = blockIdx.x * 256 + threadIdx.x;
    int d = gid % DINNER;
    int t = gid / DINNER;
    if (t >= NTOK) return;
    int l = t & (SEQ - 1);
    int tb = t - l;
    float4 w = ((const float4*)cw)[d];
    const float* wp = (const float*)&w;
    float acc = cb[d];
    #pragma unroll
    for (int k = 0; k < 4; ++k) {
        int lk = l - 3 + k;
        float v = (lk >= 0) ? xz[(tb + lk) * (2 * DINNER) + d] : 0.f;
        acc = fmaf(wp[k], v, acc);
    }
    float sv = acc / (1.f + expf(-acc));
    xs[t * DINNER + d] = sv;
    xsb[t * DINNER + d] = f2bf(sv);
}

// ---------------- per-layer weight prep: dtp_w -> bf16 [1536][64], xp_w[:48]^T -> bf16 [1536][64] ----------------
__global__ __launch_bounds__(256) void prep_wdt_kernel(const float* __restrict__ dtp_w,
                                                       const float* __restrict__ xp_w,
                                                       unsigned short* __restrict__ dtpwb,
                                                       unsigned short* __restrict__ xp48T) {
    int gid = blockIdx.x * 256 + threadIdx.x;   // 1536*64
    int rr = gid >> 6, k = gid & 63;
    dtpwb[gid] = (k < 48) ? f2bf(dtp_w[rr * 48 + k]) : (unsigned short)0;
    xp48T[gid] = (k < 48) ? f2bf(xp_w[k * DINNER + rr]) : (unsigned short)0;
}

// ---------------- B/C projection, split-K: part[kc][t][32] = xs[t, kc*128:+128] . xp_w[48+j, same] ----------------
__global__ __launch_bounds__(256) void bc_partial_kernel(const float* __restrict__ xs,
                                                         const float* __restrict__ bcw,  // x_proj_w + 48*1536 (layer base)
                                                         float* __restrict__ part) {
    const int kc = blockIdx.x;            // 0..11
    const int mt = blockIdx.y;            // 0..15
    const int j  = threadIdx.x & 31;
    const int rg = threadIdx.x >> 5;      // 0..7
    const float* brow = bcw + (size_t)j * DINNER + kc * 128;
    #pragma unroll 1
    for (int rr = 0; rr < 16; ++rr) {
        int row = mt * 128 + rg * 16 + rr;
        const float* arow = xs + (size_t)row * DINNER + kc * 128;
        float acc = 0.f;
        #pragma unroll
        for (int qq = 0; qq < 32; ++qq) {
            float4 av = ((const float4*)arow)[qq];
            float4 bv = ((const float4*)brow)[qq];
            acc = fmaf(av.x, bv.x, acc); acc = fmaf(av.y, bv.y, acc);
            acc = fmaf(av.z, bv.z, acc); acc = fmaf(av.w, bv.w, acc);
        }
        part[((size_t)kc * NTOK + row) * 32 + j] = acc;
    }
}

__global__ __launch_bounds__(256) void bc_reduce_kernel(const float* __restrict__ part,
                                                        float* __restrict__ xbc) {
    int gid = blockIdx.x * 256 + threadIdx.x;   // 65536
    float s = 0.f;
    #pragma unroll
    for (int kc = 0; kc < 12; ++kc) s += part[(size_t)kc * (NTOK * 32) + gid];
    xbc[gid] = s;
}

// ---------------- transpose dt,xs : [T][D] -> [B][D][L] (LDS 32x32 tiles) ----------------
__global__ __launch_bounds__(256) void transpose2_kernel(const float* __restrict__ dtb,
                                                         const float* __restrict__ xs,
                                                         float* __restrict__ dt_t,
                                                         float* __restrict__ xs_t) {
    __shared__ float t0[32][33];
    __shared__ float t1[32][33];
    const int tid = threadIdx.x;
    const int tx = tid & 31, ty = tid >> 5;
    const int tbase = blockIdx.x * 32;
    const int dbase = blockIdx.y * 32;
    #pragma unroll
    for (int i = 0; i < 4; ++i) {
        int t = tbase + ty + i * 8;
        t0[ty + i * 8][tx] = dtb[(size_t)t * DINNER + dbase + tx];
        t1[ty + i * 8][tx] = xs[(size_t)t * DINNER + dbase + tx];
    }
    __syncthreads();
    const int b = tbase >> 10;
    const int l0 = tbase & (SEQ - 1);
    #pragma unroll
    for (int i = 0; i < 4; ++i) {
        int d = dbase + ty + i * 8;
        size_t o = (size_t)(b * DINNER + d) * SEQ + l0 + tx;
        dt_t[o] = t0[tx][ty + i * 8];
        xs_t[o] = t1[tx][ty + i * 8];
    }
}

// ---------------- chunk-parallel selective scan ----------------
__global__ __launch_bounds__(256) void scan2_kernel(const float* __restrict__ dt_t,
                                                    const float* __restrict__ x_t,
                                                    const float* __restrict__ xbc,   // [T][32]: B@0, C@16
                                                    const float* __restrict__ A_log,
                                                    const float* __restrict__ Dp,
                                                    float* __restrict__ y_t) {
    const int bd = blockIdx.x;
    const int d = bd % DINNER;
    const int b = bd / DINNER;
    const int tid = threadIdx.x;
    const int c = tid >> 4;
    const int n = tid & 15;

    const float* dtp = dt_t + (size_t)bd * SEQ + c * 64;
    const float* xp  = x_t  + (size_t)bd * SEQ + c * 64;
    const float* xb  = xbc + (size_t)(b * SEQ + c * 64) * 32;
    const float A = -expf(A_log[d * NSTATE + n]);

    float a = 1.f, h = 0.f;
    #pragma unroll 4
    for (int qq = 0; qq < 16; ++qq) {
        float4 dq = ((const float4*)dtp)[qq];
        float4 xq = ((const float4*)xp)[qq];
        const float* dv = (const float*)&dq;
        const float* xv = (const float*)&xq;
        #pragma unroll
        for (int j = 0; j < 4; ++j) {
            int l = qq * 4 + j;
            float Bv = xb[l * 32 + n];
            float dA = expf(dv[j] * A);
            a *= dA;
            h = fmaf(h, dA, dv[j] * Bv * xv[j]);
        }
    }

    __shared__ float sa[16][16];
    __shared__ float sb[16][16];
    sa[c][n] = a; sb[c][n] = h;
    __syncthreads();
    if (tid < 16) {
        float hrun = 0.f;
        #pragma unroll
        for (int cc = 0; cc < 16; ++cc) {
            float av = sa[cc][tid];
            float bv = sb[cc][tid];
            sa[cc][tid] = hrun;
            hrun = fmaf(av, hrun, bv);
        }
    }
    __syncthreads();

    float hh = sa[c][n];
    const float Dv = Dp[d];
    float* yo = y_t + (size_t)bd * SEQ + c * 64;
    #pragma unroll 4
    for (int qq = 0; qq < 16; ++qq) {
        float4 dq = ((const float4*)dtp)[qq];
        float4 xq = ((const float4*)xp)[qq];
        const float* dv = (const float*)&dq;
        const float* xv = (const float*)&xq;
        #pragma unroll
        for (int j = 0; j < 4; ++j) {
            int l = qq * 4 + j;
            float Bv = xb[l * 32 + n];
            float Cv = xb[l * 32 + 16 + n];
            float dA = expf(dv[j] * A);
            hh = fmaf(hh, dA, dv[j] * Bv * xv[j]);
            float p = hh * Cv;
            p += __shfl_xor(p, 1, 16);
            p += __shfl_xor(p, 2, 16);
            p += __shfl_xor(p, 4, 16);
            p += __shfl_xor(p, 8, 16);
            if (n == 0) yo[l] = fmaf(Dv, xv[j], p);
        }
    }
}

// ---------------- fused gate + transpose + bf16 ----------------
__global__ __launch_bounds__(256) void gate_tr_kernel(const float* __restrict__ y_t,
                                                      const float* __restrict__ xz,
                                                      unsigned short* __restrict__ g) {
    __shared__ float ty_[32][33];
    const int tid = threadIdx.x;
    const int tx = tid & 31, ty = tid >> 5;
    const int tbase = blockIdx.x * 32;
    const int dbase = blockIdx.y * 32;
    const int b = tbase >> 10;
    const int l0 = tbase & (SEQ - 1);
    #pragma unroll
    for (int i = 0; i < 4; ++i) {
        int d = dbase + ty + i * 8;
        ty_[ty + i * 8][tx] = y_t[(size_t)(b * DINNER + d) * SEQ + l0 + tx];
    }
    __syncthreads();
    #pragma unroll
    for (int i = 0; i < 4; ++i) {
        int t = tbase + ty + i * 8;
        int d = dbase + tx;
        float z = xz[(size_t)t * (2 * DINNER) + DINNER + d];
        float yv = ty_[tx][ty + i * 8];
        float gv = yv * z / (1.f + expf(-z));
        g[(size_t)t * DINNER + d] = f2bf(gv);
    }
}

extern "C" void kernel_launch(void* const* d_in, const int* in_sizes, int n_in,
                              void* d_out, int out_size, void* d_ws, size_t ws_size,
                              hipStream_t stream) {
    const int*   tokens     = (const int*)d_in[0];
    const float* wte        = (const float*)d_in[1];
    const float* in_proj_w  = (const float*)d_in[2];
    const float* conv_w     = (const float*)d_in[3];
    const float* conv_b     = (const float*)d_in[4];
    const float* x_proj_w   = (const float*)d_in[5];
    const float* dt_proj_w  = (const float*)d_in[6];
    const float* dt_proj_b  = (const float*)d_in[7];
    const float* out_proj_w = (const float*)d_in[8];
    const float* A_log      = (const float*)d_in[9];
    const float* Dparam     = (const float*)d_in[10];
    const float* lm_head_w  = (const float*)d_in[11];
    float* out = (float*)d_out;

    // fp32 workspace
    float* ws   = (float*)d_ws;
    float* x    = ws;                          // NTOK*DMODEL
    float* xz   = x    + NTOK * DMODEL;        // NTOK*2*DINNER
    float* xs   = xz   + NTOK * 2 * DINNER;    // NTOK*DINNER
    float* dtb  = xs   + NTOK * DINNER;        // NTOK*DINNER
    float* dt_t = dtb  + NTOK * DINNER;        // NTOK*DINNER
    float* xs_t = dt_t + NTOK * DINNER;        // NTOK*DINNER
    float* xbc  = xs_t + NTOK * DINNER;        // NTOK*32
    float* y_t    = dtb;                       // alias: dtb dead after transpose2
    float* bcpart = dt_t;                      // alias: consumed before transpose2 writes dt_t
    // bf16 workspace
    unsigned short* xnb    = (unsigned short*)(xbc + NTOK * 32);
    unsigned short* xsb    = xnb    + NTOK * DMODEL;
    unsigned short* gb     = xsb    + NTOK * DINNER;
    unsigned short* inwb   = gb     + NTOK * DINNER;
    unsigned short* outwb  = inwb   + 2 * 2 * DINNER * DMODEL;
    unsigned short* lmwb   = outwb  + 2 * DMODEL * DINNER;
    unsigned short* dtpwb  = lmwb   + (size_t)VOCAB * DMODEL;   // 1536*64 (per-layer reuse)
    unsigned short* xp48Tb = dtpwb  + DINNER * 64;              // 1536*64
    unsigned short* Wdtb   = xp48Tb + DINNER * 64;              // 1536*1536

    // weight conversions (once per call)
    {
        int n8 = 2 * 2 * DINNER * DMODEL / 8;
        cvt_bf16_kernel<<<(n8 + 255) / 256, 256, 0, stream>>>(in_proj_w, inwb, n8);
        n8 = 2 * DMODEL * DINNER / 8;
        cvt_bf16_kernel<<<(n8 + 255) / 256, 256, 0, stream>>>(out_proj_w, outwb, n8);
        n8 = VOCAB * DMODEL / 8;
        cvt_bf16_kernel<<<(n8 + 255) / 256, 256, 0, stream>>>(lm_head_w, lmwb, n8);
    }

    // embed
    embed_kernel<<<NTOK * (DMODEL / 4) / 256, 256, 0, stream>>>(tokens, wte, x);

    for (int i = 0; i < NLAYER; ++i) {
        const unsigned short* inw = inwb + (size_t)i * 2 * DINNER * DMODEL;
        const float* cw   = conv_w     + (size_t)i * DINNER * 4;
        const float* cb   = conv_b     + (size_t)i * DINNER;
        const float* xpw  = x_proj_w   + (size_t)i * (DTRANK + 2 * NSTATE) * DINNER;
        const float* dtpw = dt_proj_w  + (size_t)i * DINNER * DTRANK;
        const float* dtpb = dt_proj_b  + (size_t)i * DINNER;
        const unsigned short* outw = outwb + (size_t)i * DMODEL * DINNER;
        const float* alog = A_log      + (size_t)i * DINNER * NSTATE;
        const float* dpar = Dparam     + (size_t)i * DINNER;

        // rmsnorm -> bf16
        rmsnorm_bf16_kernel<<<NTOK, 256, 0, stream>>>(x, xnb);
        // xz = xn @ in_w^T : (2048, 3072) [128^2 MFMA]
        gemm_bf16<<<(NTOK / 128) * (2 * DINNER / 128), 256, 0, stream>>>(
            xnb, DMODEL, inw, DMODEL, xz, 2 * DINNER, DMODEL, NTOK / 128);
        // conv + silu -> xs (fp32) + xsb (bf16)
        conv_silu_kernel<<<NTOK * DINNER / 256, 256, 0, stream>>>(xz, cw, cb, xs, xsb);
        // Wdt = dtp_w @ xp_w[:48]  (fused dt projection), K padded 48->64
        prep_wdt_kernel<<<DINNER * 64 / 256, 256, 0, stream>>>(dtpw, xpw, dtpwb, xp48Tb);
        gemm64<3><<<(DINNER / 64) * (DINNER / 64), 256, 0, stream>>>(
            dtpwb, 64, xp48Tb, 64, Wdtb, DINNER, 64, DINNER / 64, nullptr);
        // dt = softplus(xs @ Wdt^T + b) : (2048, 1536) [64^2 MFMA]
        gemm64<1><<<(NTOK / 64) * (DINNER / 64), 256, 0, stream>>>(
            xsb, DINNER, Wdtb, DINNER, dtb, DINNER, DINNER, NTOK / 64, dtpb);
        // B/C = xs @ xp_w[48:80]^T : (2048, 32) split-K fp32
        bc_partial_kernel<<<dim3(12, 16), 256, 0, stream>>>(xs, xpw + 48 * DINNER, bcpart);
        bc_reduce_kernel<<<NTOK * 32 / 256, 256, 0, stream>>>(bcpart, xbc);
        // transpose dt, xs -> [B][D][L]
        transpose2_kernel<<<dim3(NTOK / 32, DINNER / 32), 256, 0, stream>>>(dtb, xs, dt_t, xs_t);
        // chunk-parallel scan -> y_t
        scan2_kernel<<<BATCH * DINNER, 256, 0, stream>>>(dt_t, xs_t, xbc, alog, dpar, y_t);
        // fused gate + transpose back + bf16 -> gb [T][D]
        gate_tr_kernel<<<dim3(NTOK / 32, DINNER / 32), 256, 0, stream>>>(y_t, xz, gb);
        // x += g @ out_w^T : (2048, 768) [64^2 MFMA accumulate]
        gemm64<2><<<(NTOK / 64) * (DMODEL / 64), 256, 0, stream>>>(
            gb, DINNER, outw, DINNER, x, DMODEL, DINNER, NTOK / 64, nullptr);
    }

    // final norm + lm_head [128^2 MFMA]
    rmsnorm_bf16_kernel<<<NTOK, 256, 0, stream>>>(x, xnb);
    gemm_bf16<<<(NTOK / 128) * (VOCAB / 128), 256, 0, stream>>>(
        xnb, DMODEL, lmwb, DMODEL, out, VOCAB, DMODEL, NTOK / 128);
}